// Round 7
// baseline (3339.957 us; speedup 1.0000x reference)
//
#include <hip/hip_runtime.h>
#include <stdint.h>

#define DI __device__ __forceinline__

typedef __bf16 bf16x8 __attribute__((ext_vector_type(8)));
typedef float f32x4 __attribute__((ext_vector_type(4)));
typedef unsigned short u16x4 __attribute__((ext_vector_type(4)));
typedef unsigned short u16x8 __attribute__((ext_vector_type(8)));

static constexpr int BB = 16;     // batch
static constexpr int NP = 2048;   // points
static constexpr int FP = 1024;   // padded F1 (=1000)
static constexpr int K3 = 3072;   // 3*FP
static constexpr int RR = 20;     // Reeb nodes
static constexpr int GG = 128;    // group size
static constexpr int RK = 6144;   // 6*FP
static constexpr int MRp = 384;   // padded 16*20=320 -> 384
static constexpr int NJ = 16;     // j-chunks for lap passes
static constexpr int NI = 8;      // i-chunks for rnorm stage 1
static constexpr int NJ2 = 8;     // j-chunks for adjx

DI float b2f(unsigned short u) {
    unsigned v = ((unsigned)u) << 16;
    return __builtin_bit_cast(float, v);
}
DI unsigned short f2b(float f) {
    unsigned u = __builtin_bit_cast(unsigned, f);
    unsigned r = (u + 0x7FFFu + ((u >> 16) & 1u)) >> 16;
    return (unsigned short)r;
}

// ---------------------------------------------------------------------------
// BT-form bf16 MFMA GEMM: C = A @ B^T, 128x128 tile, BK=32.
// DIRECT-TO-REGISTER K-loop: both A and B fragments are contiguous 16B global
// loads per lane (BT layout), so no LDS, no barriers. Ping-pong register
// fragment sets; loads for tile t+2 issue between MFMA batches -> compiler
// emits s_waitcnt vmcnt(8) (never 0): waves fully decoupled, AITER-style.
// L1 absorbs intra-block fragment sharing; L2 absorbs cross-tile re-reads.
// XCD-pinned strip-mined block swizzle for L2 locality.
// ---------------------------------------------------------------------------
enum { EADJ = 0, ELAP1 = 1, ELAP2 = 2, EBRELU = 3 };

template <int EPI>
__global__ __launch_bounds__(256) void gemm_bt(
    const unsigned short* __restrict__ A, long sA, int lda,
    const unsigned short* __restrict__ Bt, long sB, int ldb,
    unsigned short* __restrict__ C, long sC, int ldc, int K,
    const float* __restrict__ sq,        // EADJ: sq norms; ELAP*: dv (per-batch NP)
    float* __restrict__ rowsum,          // EADJ
    const unsigned short* __restrict__ aux, long sAux, int ldaux,  // ELAP1/2: cat
    const float* __restrict__ bias, int biasN)                     // EBRELU
{
    const int tid = threadIdx.x;

    // ---- XCD-pinned strip-mined swizzle ----
    int gx = gridDim.x, gy = gridDim.y;
    int flat = blockIdx.x + gx * (blockIdx.y + gy * blockIdx.z);
    int tpb = gx * gy;
    int T = tpb * gridDim.z;
    int bz, ty, tx;
    if (((T & 7) == 0) && ((gx & 7) == 0)) {
        int per = T >> 3;
        int g = (flat & 7) * per + (flat >> 3);
        bz = g / tpb;
        int t = g - bz * tpb;
        int strip = gy << 3;          // tiles per 8-wide col-group
        int cg = t / strip;
        int r = t - cg * strip;
        ty = r >> 3;
        tx = (cg << 3) + (r & 7);
    } else {
        bz = blockIdx.z; ty = blockIdx.y; tx = blockIdx.x;
    }
    const int rowBase = ty * 128;
    const int colBase = tx * 128;

    const int lane = tid & 63;
    const int q = lane >> 4;
    const int l15 = lane & 15;
    const int wave = tid >> 6;
    const int wr = (wave >> 1) * 64;
    const int wc = (wave & 1) * 64;

    // per-lane fragment base pointers (16B-contiguous loads)
    const unsigned short* Ap[4];
    const unsigned short* Bp[4];
#pragma unroll
    for (int mi = 0; mi < 4; mi++)
        Ap[mi] = A + (long)bz * sA + (long)(rowBase + wr + mi * 16 + l15) * lda + q * 8;
#pragma unroll
    for (int ni = 0; ni < 4; ni++)
        Bp[ni] = Bt + (long)bz * sB + (long)(colBase + wc + ni * 16 + l15) * ldb + q * 8;

    f32x4 acc[4][4];
#pragma unroll
    for (int i = 0; i < 4; i++)
#pragma unroll
        for (int j = 0; j < 4; j++) acc[i][j] = f32x4{0.f, 0.f, 0.f, 0.f};

    bf16x8 af0[4], bf0[4], af1[4], bf1[4];
    auto loadf = [&](int kb, bf16x8* af, bf16x8* bf) {
#pragma unroll
        for (int mi = 0; mi < 4; mi++) af[mi] = *(const bf16x8*)(Ap[mi] + kb);
#pragma unroll
        for (int ni = 0; ni < 4; ni++) bf[ni] = *(const bf16x8*)(Bp[ni] + kb);
    };
    auto domfma = [&](bf16x8* af, bf16x8* bf) {
#pragma unroll
        for (int mi = 0; mi < 4; mi++)
#pragma unroll
            for (int ni = 0; ni < 4; ni++)
                acc[mi][ni] = __builtin_amdgcn_mfma_f32_16x16x32_bf16(
                    af[mi], bf[ni], acc[mi][ni], 0, 0, 0);
    };

    const int nIter = K >> 5;   // even for all K used here (32/64/96/192)
    loadf(0, af0, bf0);
    loadf(32, af1, bf1);
    for (int t = 0; t < nIter; t += 2) {
        domfma(af0, bf0);                      // waits tile t; t+1 still in flight
        if (t + 2 < nIter) loadf((t + 2) << 5, af0, bf0);
        domfma(af1, bf1);                      // waits tile t+1; t+2 in flight
        if (t + 3 < nIter) loadf((t + 3) << 5, af1, bf1);
    }

    // Epilogue. C/D layout: col = lane&15, row = (lane>>4)*4 + reg (m89).
    const float* sqb = (EPI != EBRELU) ? (sq + (long)bz * NP) : nullptr;
#pragma unroll
    for (int mi = 0; mi < 4; mi++) {
#pragma unroll
        for (int rg = 0; rg < 4; rg++) {
            const int grow = rowBase + wr + mi * 16 + q * 4 + rg;
            float rsumv = 0.f;
            float di = 0.f;
            if (EPI == ELAP1 || EPI == ELAP2) di = sqb[grow];
#pragma unroll
            for (int ni = 0; ni < 4; ni++) {
                const int gcol = colBase + wc + ni * 16 + l15;
                float v = acc[mi][ni][rg];
                long cidx = (long)bz * sC + (long)grow * ldc + gcol;
                if (EPI == EADJ) {
                    float e = __expf(2.f * v - sqb[grow] - sqb[gcol]);
                    C[cidx] = f2b(e);
                    rsumv += e;
                } else if (EPI == ELAP1) {
                    // X1 = out - D*(A*(D*out))
                    float o = b2f(aux[(long)bz * sAux + (long)grow * ldaux + gcol]);
                    C[cidx] = f2b(o - di * v);
                } else if (EPI == ELAP2) {
                    // X2 = 2*(X1 - D*(A*(D*X1))) - out
                    long abase = (long)bz * sAux + (long)grow * ldaux + gcol;
                    float o0 = b2f(aux[abase]);          // out  (cat block0)
                    float o1 = b2f(aux[abase + 1024]);   // X1   (cat block1)
                    C[cidx] = f2b(2.f * (o1 - di * v) - o0);
                } else {  // EBRELU
                    float bv = (gcol < biasN) ? bias[gcol] : 0.f;
                    float o = v + bv;
                    C[cidx] = f2b(o > 0.f ? o : 0.f);
                }
            }
            if (EPI == EADJ) {
                rsumv += __shfl_xor(rsumv, 1);
                rsumv += __shfl_xor(rsumv, 2);
                rsumv += __shfl_xor(rsumv, 4);
                rsumv += __shfl_xor(rsumv, 8);
                if (l15 == 0) atomicAdd(&rowsum[(long)bz * NP + grow], rsumv);
            }
        }
    }
}

// ---------------------------------------------------------------------------
// Scaled bf16 transpose: dst[c][r] = dv[r] * src[r][c]; grid (cols/64, rows/64, C)
// ---------------------------------------------------------------------------
__global__ __launch_bounds__(256) void k_trs(
    const unsigned short* __restrict__ src, long sS, int ldS,
    const float* __restrict__ dv,
    unsigned short* __restrict__ dst, long sD, int ldD)
{
    __shared__ unsigned short t[64][72];
    const int b = blockIdx.z;
    const int c0 = blockIdx.x * 64, r0 = blockIdx.y * 64;
    const unsigned short* S = src + (long)b * sS;
    const float* dvb = dv + (long)b * NP;
    unsigned short* D = dst + (long)b * sD;
    const int tx = threadIdx.x & 7, ty = threadIdx.x >> 3;
#pragma unroll
    for (int p = 0; p < 2; p++) {
        int r = ty + p * 32;
        float s = dvb[r0 + r];
        u16x8 v = *(const u16x8*)(S + (long)(r0 + r) * ldS + c0 + tx * 8);
#pragma unroll
        for (int k = 0; k < 8; k++) t[tx * 8 + k][r] = f2b(s * b2f(v[k]));
    }
    __syncthreads();
#pragma unroll
    for (int p = 0; p < 2; p++) {
        int r = ty + p * 32;
        u16x8 v;
#pragma unroll
        for (int k = 0; k < 8; k++) v[k] = t[r][tx * 8 + k];
        *(u16x8*)(D + (long)(c0 + r) * ldD + r0 + tx * 8) = v;
    }
}

// fp32 tiled transpose: dst[c*R + r] = src[r*C + c].  grid (ceil(C/32), ceil(R/32)),
// block dim3(32,8).
__global__ void k_trf32(const float* __restrict__ src, int R, int C,
                        float* __restrict__ dst)
{
    __shared__ float t[32][33];
    const int c0 = blockIdx.x * 32, r0 = blockIdx.y * 32;
#pragma unroll
    for (int p = 0; p < 4; p++) {
        int r = r0 + threadIdx.y + p * 8;
        int c = c0 + threadIdx.x;
        t[threadIdx.y + p * 8][threadIdx.x] =
            (r < R && c < C) ? src[(long)r * C + c] : 0.f;
    }
    __syncthreads();
#pragma unroll
    for (int p = 0; p < 4; p++) {
        int c = c0 + threadIdx.y + p * 8;   // dst row
        int r = r0 + threadIdx.x;           // dst col
        if (c < C && r < R) dst[(long)c * R + r] = t[threadIdx.x][threadIdx.y + p * 8];
    }
}

// ---------------------------------------------------------------------------
// Permuted+transposed weight fill: dst[o][s*FP+f] = W[(f*KK+s)*1000+o], 0-pad.
// grid (16, dstld/64), 256 thr.
// ---------------------------------------------------------------------------
__global__ __launch_bounds__(256) void k_wperm(
    const float* __restrict__ W, unsigned short* __restrict__ dst, int KK, int dstld)
{
    __shared__ float tile[64][65];
    const int o0 = blockIdx.x * 64;
    const int kk0 = blockIdx.y * 64;
    const int s = kk0 >> 10;
    const int fbase = kk0 & 1023;
    const int ci = threadIdx.x & 63;
    const int ri = threadIdx.x >> 6;
#pragma unroll 4
    for (int p = 0; p < 16; p++) {
        int fi = fbase + ri + p * 4;
        int oi = o0 + ci;
        float v = 0.f;
        if (fi < 1000 && oi < 1000) v = W[((long)fi * KK + s) * 1000 + oi];
        tile[ri + p * 4][ci] = v;
    }
    __syncthreads();
#pragma unroll 4
    for (int p = 0; p < 16; p++) {
        int orow = ri + p * 4;
        dst[(long)(o0 + orow) * dstld + kk0 + ci] = f2b(tile[ci][orow]);
    }
}

// zero-init of accumulators + catr pad rows (replaces hipMemsetAsync).
__global__ void k_zinit(float* __restrict__ rs2, float* __restrict__ g,
                        float* __restrict__ racc, unsigned short* __restrict__ catrpad,
                        float* __restrict__ dv1, float* __restrict__ xacc1,
                        float* __restrict__ xacc2, float* __restrict__ yacc1,
                        float* __restrict__ yacc2, float* __restrict__ l2acc)
{
    long i = (long)blockIdx.x * 256 + threadIdx.x;
    if (i < (long)BB * NP) { rs2[i] = 0.f; dv1[i] = 0.f; }
    if (i < (long)BB * FP) g[i] = 0.f;
    if (i < 64) racc[i] = 0.f;
    if (i < (long)(MRp - 320) * RK) catrpad[i] = 0;
    if (i < (long)BB * 6 * NP) { xacc1[i] = 0.f; xacc2[i] = 0.f; l2acc[i] = 0.f; }
    if (i < (long)BB * 6 * FP) { yacc1[i] = 0.f; yacc2[i] = 0.f; }
}

// x (B,N,6) -> x6t (B,6,N) + sqx (B,N).  grid (8, BB)
__global__ void k_xprep(const float* __restrict__ x, float* __restrict__ x6t,
                        float* __restrict__ sqx)
{
    const int b = blockIdx.y;
    const int j = blockIdx.x * 256 + threadIdx.x;
    float s = 0.f;
#pragma unroll
    for (int c = 0; c < 6; c++) {
        float v = x[((long)b * NP + j) * 6 + c];
        x6t[(long)b * 6 * NP + c * NP + j] = v;
        s += v * v;
    }
    sqx[(long)b * NP + j] = s;
}

// x-graph laplacian passes, j-split across NJ chunks with atomic reduction.
// grid (8, NJ, BB), block 256.
template <int MODE>
__global__ __launch_bounds__(256) void k_lapj(
    const float* __restrict__ x6t, const float* __restrict__ sqx,
    const float* __restrict__ dv1, const float* __restrict__ srct,
    float* __restrict__ acc)
{
    const int b = blockIdx.z;
    const int row = blockIdx.x * 256 + threadIdx.x;
    const int j0 = blockIdx.y * (NP / NJ);
    const float* xt = x6t + (long)b * 6 * NP;
    const float* sq = sqx + (long)b * NP;
    float xi[6];
#pragma unroll
    for (int c = 0; c < 6; c++) xi[c] = xt[c * NP + row];
    const float sqi = sq[row];
    const float* dv = (MODE >= 1) ? (dv1 + (long)b * NP) : nullptr;
    const float* st = (MODE >= 1) ? (srct + (long)b * 6 * NP) : nullptr;
    float s0 = 0.f;
    float sc[6] = {0, 0, 0, 0, 0, 0};
    for (int j = j0; j < j0 + NP / NJ; j++) {
        float dot = 0.f;
#pragma unroll
        for (int c = 0; c < 6; c++) dot += xi[c] * xt[c * NP + j];
        float e = __expf(2.f * dot - sqi - sq[j]);
        if (MODE == 0) {
            s0 += e;
        } else {
            float wgt = e * dv[j];
#pragma unroll
            for (int c = 0; c < 6; c++) sc[c] += wgt * st[c * NP + j];
        }
    }
    if (MODE == 0) {
        atomicAdd(&acc[(long)b * NP + row], s0);
    } else {
#pragma unroll
        for (int c = 0; c < 6; c++)
            atomicAdd(&acc[(long)b * 6 * NP + c * NP + row], sc[c]);
    }
}

// finalize lap pass: MODE 1: out = xi - di*sc ; MODE 2: out = 2*(x1-di*sc)-xi
// grid (8, B') block 256
template <int MODE>
__global__ void k_lfin(const float* __restrict__ x6t, const float* __restrict__ dv1,
                       const float* __restrict__ xacc, const float* __restrict__ x1t6,
                       float* __restrict__ outv)
{
    const int b = blockIdx.y;
    const int row = blockIdx.x * 256 + threadIdx.x;
    const float di = dv1[(long)b * NP + row];
#pragma unroll
    for (int c = 0; c < 6; c++) {
        long idx = (long)b * 6 * NP + c * NP + row;
        float xi = x6t[idx];
        float sc = xacc[idx];
        if (MODE == 1) outv[idx] = xi - di * sc;
        else           outv[idx] = 2.f * (x1t6[idx] - di * sc) - xi;
    }
}

// adjx: l2acc[b,c,row] += sum_{j in chunk} adj[row][j] * dv[j] * x6t[c][j]
// grid (NP/64, NJ2, C), block 256 (64 rows x 4 lanes).
__global__ __launch_bounds__(256) void k_adjx(
    const unsigned short* __restrict__ adj, const float* __restrict__ dv,
    const float* __restrict__ x6t, float* __restrict__ l2acc)
{
    __shared__ float xs[6][256];
    __shared__ float dvs[256];
    __shared__ float lsum[64][4][6];
    const int b = blockIdx.z;
    const int j0 = blockIdx.y * (NP / NJ2);   // 256-col chunk
    if (threadIdx.x < 256) dvs[threadIdx.x] = dv[(long)b * NP + j0 + threadIdx.x];
    for (int e = threadIdx.x; e < 6 * 256; e += 256) {
        int c = e >> 8, j = e & 255;
        xs[c][j] = x6t[(long)b * 6 * NP + c * NP + j0 + j];
    }
    __syncthreads();
    const int ty = threadIdx.x >> 2;
    const int tx = threadIdx.x & 3;
    const int grow = blockIdx.x * 64 + ty;
    const unsigned short* rowp = adj + (long)b * NP * NP + (long)grow * NP + j0;
    float sc[6] = {0, 0, 0, 0, 0, 0};
    for (int it = 0; it < 8; it++) {
        int col = it * 32 + tx * 8;
        u16x8 a8 = *(const u16x8*)(rowp + col);
#pragma unroll
        for (int k = 0; k < 8; k++) {
            float w = b2f(a8[k]) * dvs[col + k];
#pragma unroll
            for (int c = 0; c < 6; c++) sc[c] += w * xs[c][col + k];
        }
    }
#pragma unroll
    for (int c = 0; c < 6; c++) lsum[ty][tx][c] = sc[c];
    __syncthreads();
    for (int e = threadIdx.x; e < 64 * 6; e += 256) {
        int row = e / 6, c = e % 6;
        float t = lsum[row][0][c] + lsum[row][1][c] + lsum[row][2][c] + lsum[row][3][c];
        atomicAdd(&l2acc[(long)b * 6 * NP + (long)c * NP + blockIdx.x * 64 + row], t);
    }
}

// cheb1: out = relu([x|x1|x2]_interleaved @ W1 + b1) -> cat block0 (bf16, pad 0)
// grid (16 ntile, 4 ftile, C)
__global__ __launch_bounds__(256) void k_cheb1(
    const float* __restrict__ x, const float* __restrict__ x1t6,
    const float* __restrict__ x2t6, const float* __restrict__ W1,
    const float* __restrict__ b1, unsigned short* __restrict__ cat)
{
    __shared__ float xk[128 * 18];
    const int b = blockIdx.z;
    const int n0 = blockIdx.x * 128;
    const int f0 = blockIdx.y * 256;
    for (int e = threadIdx.x; e < 128 * 18; e += 256) {
        int rown = e / 18, c18 = e % 18;
        int cc = c18 / 3, kk = c18 % 3;
        int n = n0 + rown;
        float v;
        if (kk == 0) v = x[((long)b * NP + n) * 6 + cc];
        else if (kk == 1) v = x1t6[(long)b * 6 * NP + cc * NP + n];
        else v = x2t6[(long)b * 6 * NP + cc * NP + n];
        xk[e] = v;
    }
    __syncthreads();
    for (int gi = threadIdx.x; gi < 128 * 64; gi += 256) {
        int rown = gi >> 6;
        int f4 = f0 + (gi & 63) * 4;
        float a0 = 0, a1 = 0, a2 = 0, a3 = 0;
        if (f4 < 1000) {
            a0 = b1[f4]; a1 = b1[f4 + 1]; a2 = b1[f4 + 2]; a3 = b1[f4 + 3];
#pragma unroll
            for (int cI = 0; cI < 18; cI++) {
                float xv = xk[rown * 18 + cI];
                f32x4 w = *(const f32x4*)(W1 + cI * 1000 + f4);
                a0 += xv * w[0]; a1 += xv * w[1]; a2 += xv * w[2]; a3 += xv * w[3];
            }
            a0 = a0 > 0 ? a0 : 0; a1 = a1 > 0 ? a1 : 0;
            a2 = a2 > 0 ? a2 : 0; a3 = a3 > 0 ? a3 : 0;
        }
        u16x4 o;
        o[0] = f2b(a0); o[1] = f2b(a1); o[2] = f2b(a2); o[3] = f2b(a3);
        *(u16x4*)(cat + (long)b * NP * K3 + (long)(n0 + rown) * K3 + f4) = o;
    }
}

// sqc[b,i] = sum_f bf16(out)[b,i,f]^2   grid (NP/16, C)
__global__ void k_sqc(const unsigned short* __restrict__ cat, float* __restrict__ sqc)
{
    __shared__ float red[256];
    const int b = blockIdx.y;
    const int rloc = threadIdx.x >> 4;
    const int r = blockIdx.x * 16 + rloc;
    const int tx = threadIdx.x & 15;
    const unsigned short* p = cat + (long)b * NP * K3 + (long)r * K3;
    float s = 0.f;
    for (int it = 0; it < 8; it++) {
        int cc = it * 128 + tx * 8;
        u16x8 v = *(const u16x8*)(p + cc);
#pragma unroll
        for (int k = 0; k < 8; k++) { float f = b2f(v[k]); s += f * f; }
    }
    red[threadIdx.x] = s;
    __syncthreads();
    if (tx == 0) {
        float t = 0.f;
#pragma unroll
        for (int k = 0; k < 16; k++) t += red[rloc * 16 + k];
        sqc[(long)b * NP + r] = t;
    }
}

__global__ void k_rsqrt(float* __restrict__ p) {
    int i = blockIdx.x * 256 + threadIdx.x;
    p[i] = rsqrtf(p[i]);
}

// vertices_Reeb: vr[b,r,f] = max_g out[b, sccs[b,r,g], f].  grid (RR, C)
__global__ void k_vr(const unsigned short* __restrict__ cat,
                     const int* __restrict__ sccs, float* __restrict__ vr)
{
    const int b = blockIdx.y, r = blockIdx.x;
    const int f4 = threadIdx.x * 4;
    const int* sp = sccs + ((long)b * RR + r) * GG;
    float m0 = -1e30f, m1 = -1e30f, m2 = -1e30f, m3 = -1e30f;
    for (int g = 0; g < GG; g++) {
        int idx = sp[g];
        u16x4 v = *(const u16x4*)(cat + ((long)b * NP + idx) * K3 + f4);
        m0 = fmaxf(m0, b2f(v[0])); m1 = fmaxf(m1, b2f(v[1]));
        m2 = fmaxf(m2, b2f(v[2])); m3 = fmaxf(m3, b2f(v[3]));
    }
    float* op = vr + ((long)b * RR + r) * FP + f4;
    op[0] = m0; op[1] = m1; op[2] = m2; op[3] = m3;
}

// Reeb Chebyshev recursion (fp32), writes catr rows [b*20, b*20+20). grid (BB)
__global__ __launch_bounds__(256) void k_reeb(
    const float* __restrict__ vr, const float* __restrict__ lapR,
    unsigned short* __restrict__ catr)
{
    __shared__ float Lr[RR * RR];
    const int b = blockIdx.x;
    for (int e = threadIdx.x; e < RR * RR; e += 256) Lr[e] = lapR[(long)b * RR * RR + e];
    __syncthreads();
    for (int f = threadIdx.x; f < FP; f += 256) {
        float xa[RR], xb[RR], xc[RR];
#pragma unroll
        for (int r = 0; r < RR; r++) xa[r] = vr[((long)b * RR + r) * FP + f];
#pragma unroll
        for (int r = 0; r < RR; r++) catr[((long)b * RR + r) * RK + f] = f2b(xa[r]);
#pragma unroll
        for (int r = 0; r < RR; r++) {
            float s = 0.f;
#pragma unroll
            for (int qq = 0; qq < RR; qq++) s += Lr[r * RR + qq] * xa[qq];
            xb[r] = s;
        }
#pragma unroll
        for (int r = 0; r < RR; r++) catr[((long)b * RR + r) * RK + FP + f] = f2b(xb[r]);
        for (int st = 2; st < 6; st++) {
#pragma unroll
            for (int r = 0; r < RR; r++) {
                float s = 0.f;
#pragma unroll
                for (int qq = 0; qq < RR; qq++) s += Lr[r * RR + qq] * xb[qq];
                xc[r] = 2.f * s - xa[r];
            }
#pragma unroll
            for (int r = 0; r < RR; r++)
                catr[((long)b * RR + r) * RK + st * FP + f] = f2b(xc[r]);
#pragma unroll
            for (int r = 0; r < RR; r++) { xa[r] = xb[r]; xb[r] = xc[r]; }
        }
    }
}

// g[b,f] = max_n out2[b,n,f]  (int atomicMax; relu values >= 0, g pre-zeroed)
__global__ void k_gmax(const unsigned short* __restrict__ out2, float* __restrict__ g)
{  // grid (4, 8, C)
    const int b = blockIdx.z;
    const int f = blockIdx.x * 256 + threadIdx.x;
    const int n0 = blockIdx.y * 256;
    float m = 0.f;
    for (int n = n0; n < n0 + 256; n++)
        m = fmaxf(m, b2f(out2[((long)b * NP + n) * FP + f]));
    if (f < 1000) atomicMax((int*)&g[(long)b * FP + f], __float_as_int(m));
}

__global__ void k_grmax(const unsigned short* __restrict__ outr, float* __restrict__ gr)
{  // grid (4, BB)
    const int b = blockIdx.y;
    const int f = blockIdx.x * 256 + threadIdx.x;
    float m = -1e30f;
    for (int r = 0; r < RR; r++)
        m = fmaxf(m, b2f(outr[((long)b * RR + r) * FP + f]));
    gr[(long)b * FP + f] = (f < 1000) ? m : 0.f;
}

// rnorm stage 1: yacc[b,c,f] += sum_{i in chunk} mat[b,i,f] * v6[b,c,i]
// grid (4 fblk, NI, C) block 256
__global__ __launch_bounds__(256) void k_rnacc(
    const unsigned short* __restrict__ mat, long sM, int ldm,
    const float* __restrict__ vt6, float* __restrict__ yacc)
{
    const int b = blockIdx.z;
    const int f = blockIdx.x * 256 + threadIdx.x;
    const int i0 = blockIdx.y * (NP / NI);
    const unsigned short* mp = mat + (long)b * sM + f;
    const float* vp = vt6 + (long)b * 6 * NP;
    float a[6] = {0, 0, 0, 0, 0, 0};
    for (int i = i0; i < i0 + NP / NI; i++) {
        float o = b2f(mp[(long)i * ldm]);
#pragma unroll
        for (int c = 0; c < 6; c++) a[c] += o * vp[c * NP + i];
    }
#pragma unroll
    for (int c = 0; c < 6; c++)
        atomicAdd(&yacc[((long)b * 6 + c) * FP + f], a[c]);
}

// rnorm stage 2: racc[bi] = sum over (b,c,f) of yacc^2.  grid (2) block 256
__global__ void k_rnred(const float* __restrict__ yacc1,
                        const float* __restrict__ yacc2, float* __restrict__ racc)
{
    __shared__ float red[256];
    const float* y = (blockIdx.x == 0) ? yacc1 : yacc2;
    float s = 0.f;
    for (long e = threadIdx.x; e < (long)BB * 6 * FP; e += 256) {
        float v = y[e];
        s += v * v;
    }
    red[threadIdx.x] = s;
    __syncthreads();
    for (int st = 128; st > 0; st >>= 1) {
        if (threadIdx.x < st) red[threadIdx.x] += red[threadIdx.x + st];
        __syncthreads();
    }
    if (threadIdx.x == 0) racc[blockIdx.x] = red[0];
}

// h1 = relu([gR|g] @ Wfc1 + bfc1), wave-per-output with WT1 (512 x 2000).
// grid (128, BB) block 256 (4 waves)
__global__ __launch_bounds__(256) void k_fc1w(
    const float* __restrict__ gr, const float* __restrict__ g,
    const float* __restrict__ WT1, const float* __restrict__ bias,
    float* __restrict__ h1)
{
    const int b = blockIdx.y;
    const int lane = threadIdx.x & 63;
    const int o = blockIdx.x * 4 + (threadIdx.x >> 6);
    const float* wt = WT1 + (long)o * 2000;
    const float* grp = gr + (long)b * FP;
    const float* gp = g + (long)b * FP;
    float s = 0.f;
    for (int j0 = 0; j0 < 2000; j0 += 64) {
        int j = j0 + lane;
        if (j < 2000) {
            float fv = (j < 1000) ? grp[j] : gp[j - 1000];
            s += fv * wt[j];
        }
    }
#pragma unroll
    for (int d = 1; d < 64; d <<= 1) s += __shfl_xor(s, d);
    if (lane == 0) {
        float v = s + bias[o];
        h1[(long)b * 512 + o] = v > 0.f ? v : 0.f;
    }
}

// h2 = relu(h1 @ Wfc2 + bfc2), wave-per-output with WT2 (128 x 512).
// grid (32, BB) block 256
__global__ __launch_bounds__(256) void k_fc2w(
    const float* __restrict__ h1, const float* __restrict__ WT2,
    const float* __restrict__ bias, float* __restrict__ h2)
{
    const int b = blockIdx.y;
    const int lane = threadIdx.x & 63;
    const int o = blockIdx.x * 4 + (threadIdx.x >> 6);
    const float* wt = WT2 + (long)o * 512;
    const float* hp = h1 + (long)b * 512;
    float s = 0.f;
#pragma unroll
    for (int j0 = 0; j0 < 512; j0 += 64) s += hp[j0 + lane] * wt[j0 + lane];
#pragma unroll
    for (int d = 1; d < 64; d <<= 1) s += __shfl_xor(s, d);
    if (lane == 0) {
        float v = s + bias[o];
        h2[(long)b * 128 + o] = v > 0.f ? v : 0.f;
    }
}

// final FC + regs.  grid(2) block 256
__global__ void k_tail(const float* __restrict__ h2, const float* __restrict__ Wfc3,
                       const float* __restrict__ bfc3, const float* __restrict__ Wfc1,
                       const float* __restrict__ bfc1, const float* __restrict__ Wfc2,
                       const float* __restrict__ bfc2, const float* __restrict__ racc,
                       float* __restrict__ out)
{
    if (blockIdx.x == 0) {
        for (int e = threadIdx.x; e < 640; e += 256) {
            int row = e / 40, o = e % 40;
            float s = bfc3[o];
            for (int j = 0; j < 128; j++) s += h2[row * 128 + j] * Wfc3[j * 40 + o];
            out[e] = s;
        }
    } else {
        __shared__ float red[256];
        float s = 0.f;
        for (int j = threadIdx.x; j < 2000; j += 256) { float w = Wfc1[j * 512]; s += w * w; }
        red[threadIdx.x] = s;
        __syncthreads();
        for (int st = 128; st > 0; st >>= 1) {
            if (threadIdx.x < st) red[threadIdx.x] += red[threadIdx.x + st];
            __syncthreads();
        }
        if (threadIdx.x == 0) out[642] = red[0];
        __syncthreads();
        s = 0.f;
        for (int j = threadIdx.x; j < 512; j += 256) { float w = Wfc2[j * 128]; s += w * w; }
        red[threadIdx.x] = s;
        __syncthreads();
        for (int st = 128; st > 0; st >>= 1) {
            if (threadIdx.x < st) red[threadIdx.x] += red[threadIdx.x + st];
            __syncthreads();
        }
        if (threadIdx.x == 0) out[644] = red[0];
        __syncthreads();
        s = 0.f;
        for (int j = threadIdx.x; j < 128; j += 256) { float w = Wfc3[j * 40]; s += w * w; }
        red[threadIdx.x] = s;
        __syncthreads();
        for (int st = 128; st > 0; st >>= 1) {
            if (threadIdx.x < st) red[threadIdx.x] += red[threadIdx.x + st];
            __syncthreads();
        }
        if (threadIdx.x == 0) {
            out[646] = red[0];
            out[640] = sqrtf(racc[0]);
            out[641] = sqrtf(racc[1]);
            out[643] = bfc1[0] * bfc1[0];
            out[645] = bfc2[0] * bfc2[0];
            out[647] = bfc3[0] * bfc3[0];
        }
    }
}

// ---------------------------------------------------------------------------
extern "C" void kernel_launch(void* const* d_in, const int* in_sizes, int n_in,
                              void* d_out, int out_size, void* d_ws, size_t ws_size,
                              hipStream_t stream)
{
    (void)in_sizes; (void)n_in; (void)out_size;
    const float* x    = (const float*)d_in[0];
    const float* lapR = (const float*)d_in[1];
    const int*   sccs = (const int*)d_in[2];
    const float* W1   = (const float*)d_in[3];
    const float* b1   = (const float*)d_in[4];
    const float* W2   = (const float*)d_in[5];
    const float* b2   = (const float*)d_in[6];
    const float* Wr   = (const float*)d_in[7];
    const float* br   = (const float*)d_in[8];
    const float* Wfc1 = (const float*)d_in[9];
    const float* bfc1 = (const float*)d_in[10];
    const float* Wfc2 = (const float*)d_in[11];
    const float* bfc2 = (const float*)d_in[12];
    const float* Wfc3 = (const float*)d_in[13];
    const float* bfc3 = (const float*)d_in[14];
    float* out = (float*)d_out;

    char* w = (char*)d_ws;
    size_t used = 0;
    auto alloc = [&](size_t bytes) {
        char* p = w + used;
        used += (bytes + 255) & ~(size_t)255;
        return p;
    };
    // ---- persistent buffers (~37 MB) ----
    unsigned short* w2pt = (unsigned short*)alloc((size_t)FP * K3 * 2);
    unsigned short* wrpt = (unsigned short*)alloc((size_t)FP * RK * 2);
    unsigned short* catr = (unsigned short*)alloc((size_t)MRp * RK * 2);
    unsigned short* outr = (unsigned short*)alloc((size_t)MRp * FP * 2);
    float* vr   = (float*)alloc((size_t)BB * RR * FP * 4);
    float* x6t  = (float*)alloc((size_t)BB * 6 * NP * 4);
    float* sqx  = (float*)alloc((size_t)BB * NP * 4);
    float* dv1  = (float*)alloc((size_t)BB * NP * 4);
    float* x1t6 = (float*)alloc((size_t)BB * 6 * NP * 4);
    float* x2t6 = (float*)alloc((size_t)BB * 6 * NP * 4);
    float* xacc1= (float*)alloc((size_t)BB * 6 * NP * 4);
    float* xacc2= (float*)alloc((size_t)BB * 6 * NP * 4);
    float* l2acc= (float*)alloc((size_t)BB * 6 * NP * 4);
    float* sqc  = (float*)alloc((size_t)BB * NP * 4);
    float* rs2  = (float*)alloc((size_t)BB * NP * 4);
    float* l2xt6= (float*)alloc((size_t)BB * 6 * NP * 4);
    float* g    = (float*)alloc((size_t)BB * FP * 4);
    float* gr   = (float*)alloc((size_t)BB * FP * 4);
    float* h1   = (float*)alloc((size_t)BB * 512 * 4);
    float* h2   = (float*)alloc((size_t)BB * 128 * 4);
    float* racc = (float*)alloc(256);
    float* WT1  = (float*)alloc((size_t)512 * 2000 * 4);
    float* WT2  = (float*)alloc((size_t)128 * 512 * 4);
    float* yacc1= (float*)alloc((size_t)BB * 6 * FP * 4);
    float* yacc2= (float*)alloc((size_t)BB * 6 * FP * 4);

    // ---- choose batch chunk size C so chunk buffers fit ws ----
    const size_t PCAT = (size_t)NP * K3 * 2;   // 12.58 MB / batch
    const size_t PA   = (size_t)NP * NP * 2;   //  8.39 MB / batch (adj; out2 aliases)
    const size_t PTT  = (size_t)FP * NP * 2;   //  4.19 MB / batch
    int C = 16;
    while (C > 1 && used + (size_t)C * (PCAT + PA + PTT) + 4096 > ws_size) C >>= 1;
    if (used + (size_t)C * (PCAT + PA + PTT) + 4096 > ws_size) return;  // ws too small

    unsigned short* cat_c = (unsigned short*)alloc((size_t)C * PCAT);
    unsigned short* a_c   = (unsigned short*)alloc((size_t)C * PA);
    unsigned short* tt_c  = (unsigned short*)alloc((size_t)C * PTT);
    unsigned short* out2_c = a_c;  // alias: adj dead once G4 runs

    const long sCat = (long)NP * K3;
    const long sL2  = (long)NP * NP;
    const long sTT  = (long)FP * NP;
    const long sO2  = (long)NP * FP;

    // zero inits (ws is re-poisoned to 0xAA before every timed call)
    k_zinit<<<dim3(1536), 256, 0, stream>>>(rs2, g, racc, catr + (size_t)320 * RK,
                                            dv1, xacc1, xacc2, yacc1, yacc2, l2acc);

    // weight prep
    k_wperm<<<dim3(16, K3 / 64), 256, 0, stream>>>(W2, w2pt, 3, K3);
    k_wperm<<<dim3(16, RK / 64), 256, 0, stream>>>(Wr, wrpt, 6, RK);
    k_trf32<<<dim3(16, 63), dim3(32, 8), 0, stream>>>(Wfc1, 2000, 512, WT1);
    k_trf32<<<dim3(4, 16), dim3(32, 8), 0, stream>>>(Wfc2, 512, 128, WT2);

    // x-graph laplacian path (fp32, full batch, j-split + atomic reduce)
    k_xprep<<<dim3(8, BB), 256, 0, stream>>>(x, x6t, sqx);
    k_lapj<0><<<dim3(8, NJ, BB), 256, 0, stream>>>(x6t, sqx, nullptr, nullptr, dv1);
    k_rsqrt<<<dim3(BB * NP / 256), 256, 0, stream>>>(dv1);
    k_lapj<1><<<dim3(8, NJ, BB), 256, 0, stream>>>(x6t, sqx, dv1, x6t, xacc1);
    k_lfin<1><<<dim3(8, BB), 256, 0, stream>>>(x6t, dv1, xacc1, nullptr, x1t6);
    k_lapj<2><<<dim3(8, NJ, BB), 256, 0, stream>>>(x6t, sqx, dv1, x1t6, xacc2);
    k_lfin<2><<<dim3(8, BB), 256, 0, stream>>>(x6t, dv1, xacc2, x1t6, x2t6);

    for (int c0 = 0; c0 < BB; c0 += C) {
        const float* xc  = x     + (long)c0 * NP * 6;
        const float* x6c = x6t   + (long)c0 * 6 * NP;
        const float* x1c = x1t6  + (long)c0 * 6 * NP;
        const float* x2c = x2t6  + (long)c0 * 6 * NP;
        float*       sqcc= sqc   + (long)c0 * NP;
        float*       rsc = rs2   + (long)c0 * NP;
        float*       l2ac= l2acc + (long)c0 * 6 * NP;
        float*       l2xc= l2xt6 + (long)c0 * 6 * NP;

        // cheb1 -> cat block0 (out, bf16); sqc
        k_cheb1<<<dim3(16, 4, C), 256, 0, stream>>>(xc, x1c, x2c, W1, b1, cat_c);
        k_sqc<<<dim3(NP / 16, C), 256, 0, stream>>>(cat_c, sqcc);

        // G1: adj = exp(2*out@out^T - sq_i - sq_j), rowsums -> rsc; dv = rsqrt
        gemm_bt<EADJ><<<dim3(16, 16, C), 256, 0, stream>>>(
            cat_c, sCat, K3, cat_c, sCat, K3, a_c, sL2, NP, FP,
            sqcc, rsc, nullptr, 0, 0, nullptr, 0);
        k_rsqrt<<<dim3(C * NP / 256), 256, 0, stream>>>(rsc);

        // L2@x for reg-norm: l2x = x - D*(A*(D*x))   (reads adj once, no write-back)
        k_adjx<<<dim3(NP / 64, NJ2, C), 256, 0, stream>>>(a_c, rsc, x6c, l2ac);
        k_lfin<1><<<dim3(8, C), 256, 0, stream>>>(x6c, rsc, l2ac, nullptr, l2xc);

        // G2: X1 = out - D*(A*(D*out))  (B = (D*out)^T via scaled transpose)
        k_trs<<<dim3(16, 32, C), 256, 0, stream>>>(cat_c, sCat, K3, rsc, tt_c, sTT, NP);
        gemm_bt<ELAP1><<<dim3(8, 16, C), 256, 0, stream>>>(
            a_c, sL2, NP, tt_c, sTT, NP, cat_c + 1024, sCat, K3, NP,
            rsc, nullptr, cat_c, sCat, K3, nullptr, 0);

        // G3: X2 = 2*(X1 - D*(A*(D*X1))) - out
        k_trs<<<dim3(16, 32, C), 256, 0, stream>>>(cat_c + 1024, sCat, K3, rsc, tt_c, sTT, NP);
        gemm_bt<ELAP2><<<dim3(8, 16, C), 256, 0, stream>>>(
            a_c, sL2, NP, tt_c, sTT, NP, cat_c + 2048, sCat, K3, NP,
            rsc, nullptr, cat_c, sCat, K3, nullptr, 0);

        // G4: out2 = relu(cat @ W2perm^T + b2)   (out2 overwrites adj region)
        gemm_bt<EBRELU><<<dim3(8, 16, C), 256, 0, stream>>>(
            cat_c, sCat, K3, w2pt, 0, K3, out2_c, sO2, FP, K3,
            nullptr, nullptr, nullptr, 0, 0, b2, 1000);

        // pools + regs for this chunk
        k_vr<<<dim3(RR, C), 256, 0, stream>>>(
            cat_c, sccs + (long)c0 * RR * GG, vr + (long)c0 * RR * FP);
        k_gmax<<<dim3(4, 8, C), 256, 0, stream>>>(out2_c, g + (long)c0 * FP);
        k_rnacc<<<dim3(4, NI, C), 256, 0, stream>>>(
            cat_c, sCat, K3, x1c, yacc1 + (long)c0 * 6 * FP);
        k_rnacc<<<dim3(4, NI, C), 256, 0, stream>>>(
            out2_c, sO2, FP, l2xc, yacc2 + (long)c0 * 6 * FP);
    }

    // Reeb branch (full batch)
    k_reeb<<<dim3(BB), 256, 0, stream>>>(vr, lapR, catr);
    gemm_bt<EBRELU><<<dim3(8, 3, 1), 256, 0, stream>>>(
        catr, 0, RK, wrpt, 0, RK, outr, 0, FP, RK,
        nullptr, nullptr, nullptr, 0, 0, br, 1000);
    k_grmax<<<dim3(4, BB), 256, 0, stream>>>(outr, gr);

    // regs stage 2 + FC head
    k_rnred<<<dim3(2), 256, 0, stream>>>(yacc1, yacc2, racc);
    k_fc1w<<<dim3(128, BB), 256, 0, stream>>>(gr, g, WT1, bfc1, h1);
    k_fc2w<<<dim3(32, BB), 256, 0, stream>>>(h1, WT2, bfc2, h2);
    k_tail<<<dim3(2), 256, 0, stream>>>(h2, Wfc3, bfc3, Wfc1, bfc1, Wfc2, bfc2, racc, out);
}

// Round 8
// 2234.544 us; speedup vs baseline: 1.4947x; 1.4947x over previous
//
#include <hip/hip_runtime.h>
#include <stdint.h>

#define DI __device__ __forceinline__

typedef __bf16 bf16x8 __attribute__((ext_vector_type(8)));
typedef float f32x4 __attribute__((ext_vector_type(4)));
typedef unsigned short u16x4 __attribute__((ext_vector_type(4)));
typedef unsigned short u16x8 __attribute__((ext_vector_type(8)));

static constexpr int BB = 16;     // batch
static constexpr int NP = 2048;   // points
static constexpr int FP = 1024;   // padded F1 (=1000)
static constexpr int K3 = 3072;   // 3*FP
static constexpr int RR = 20;     // Reeb nodes
static constexpr int GG = 128;    // group size
static constexpr int RK = 6144;   // 6*FP
static constexpr int MRp = 384;   // padded 16*20=320 -> 384
static constexpr int NJ = 32;     // j-chunks for lap passes
static constexpr int NI = 8;      // i-chunks for rnorm stage 1
static constexpr int NJ2 = 8;     // j-chunks for adjx

DI float b2f(unsigned short u) {
    unsigned v = ((unsigned)u) << 16;
    return __builtin_bit_cast(float, v);
}
DI unsigned short f2b(float f) {
    unsigned u = __builtin_bit_cast(unsigned, f);
    unsigned r = (u + 0x7FFFu + ((u >> 16) & 1u)) >> 16;
    return (unsigned short)r;
}

DI void glds16(const unsigned short* g, unsigned short* l) {
    __builtin_amdgcn_global_load_lds(
        (const __attribute__((address_space(1))) void*)g,
        (__attribute__((address_space(3))) void*)l, 16, 0, 0);
}

// Manual sync (CK-style): memory-clobber asm = compiler fence; explicit vmcnt
// avoids __syncthreads' vmcnt(0) drain of in-flight prefetches.
#define SYNC_VM4() asm volatile("s_waitcnt vmcnt(4)\n\ts_barrier" ::: "memory")
#define SYNC_VM0() asm volatile("s_waitcnt vmcnt(0)\n\ts_barrier" ::: "memory")
#define SYNC_LGKM() asm volatile("s_waitcnt lgkmcnt(0)\n\ts_barrier" ::: "memory")

// ---------------------------------------------------------------------------
// BT-form bf16 MFMA GEMM: C = A @ B^T, 128x128 tile, BK=32, double-buffered
// LDS (2 x 16 KB) with manual vmcnt(4) sync. This structure measured 226 us /
// MfmaUtil 18.7% — its plateau: triple-buffer (R6) neutral, no-LDS
// direct-register (R7) regressed to 374 us (fragment loads = 16 scattered
// 64B lines/instr, TCP-bound). Do not re-attempt those.
// XCD-pinned strip-mined block swizzle for L2 locality (404->140 MB FETCH).
// ---------------------------------------------------------------------------
enum { EADJ = 0, ELAP1 = 1, ELAP2 = 2, EBRELU = 3 };

template <int EPI>
__global__ __launch_bounds__(256) void gemm_bt(
    const unsigned short* __restrict__ A, long sA, int lda,
    const unsigned short* __restrict__ Bt, long sB, int ldb,
    unsigned short* __restrict__ C, long sC, int ldc, int K,
    const float* __restrict__ sq,        // EADJ: sq norms; ELAP*: dv (per-batch NP)
    float* __restrict__ rowsum,          // EADJ
    const unsigned short* __restrict__ aux, long sAux, int ldaux,  // ELAP1/2: cat
    const float* __restrict__ bias, int biasN)                     // EBRELU
{
    __shared__ unsigned short smem[16384];  // 2 bufs x (A 4096 | B 4096) shorts
    const int tid = threadIdx.x;

    // ---- XCD-pinned strip-mined swizzle ----
    int gx = gridDim.x, gy = gridDim.y;
    int flat = blockIdx.x + gx * (blockIdx.y + gy * blockIdx.z);
    int tpb = gx * gy;
    int T = tpb * gridDim.z;
    int bz, ty, tx;
    if (((T & 7) == 0) && ((gx & 7) == 0)) {
        int per = T >> 3;
        int g = (flat & 7) * per + (flat >> 3);
        bz = g / tpb;
        int t = g - bz * tpb;
        int strip = gy << 3;          // tiles per 8-wide col-group
        int cg = t / strip;
        int r = t - cg * strip;
        ty = r >> 3;
        tx = (cg << 3) + (r & 7);
    } else {
        bz = blockIdx.z; ty = blockIdx.y; tx = blockIdx.x;
    }
    const int rowBase = ty * 128;
    const int colBase = tx * 128;
    const unsigned short* Ab = A + (long)bz * sA + (long)rowBase * lda;
    const unsigned short* Bb = Bt + (long)bz * sB + (long)colBase * ldb;

    const int lane = tid & 63;
    const int q = lane >> 4;
    const int l15 = lane & 15;
    const int wave = tid >> 6;
    const int wr = (wave >> 1) * 64;
    const int wc = (wave & 1) * 64;

    const int r0 = tid & 127, c0 = tid >> 7;  // staging chunk (row, col8)
    const int c1 = c0 + 2;

    f32x4 acc[4][4];
#pragma unroll
    for (int i = 0; i < 4; i++)
#pragma unroll
        for (int j = 0; j < 4; j++) acc[i][j] = f32x4{0.f, 0.f, 0.f, 0.f};

    const int nIter = K >> 5;
    // prologue: stage tile 0 into buf 0
    glds16(Ab + (long)r0 * lda + c0 * 8, smem + tid * 8);
    glds16(Ab + (long)r0 * lda + c1 * 8, smem + (tid + 256) * 8);
    glds16(Bb + (long)r0 * ldb + c0 * 8, smem + 4096 + tid * 8);
    glds16(Bb + (long)r0 * ldb + c1 * 8, smem + 4096 + (tid + 256) * 8);

    for (int it = 0; it < nIter; ++it) {
        unsigned short* cur = smem + ((it & 1) << 13);
        unsigned short* nxt = smem + (((it + 1) & 1) << 13);
        if (it + 1 < nIter) {
            const int kb = (it + 1) << 5;
            glds16(Ab + (long)r0 * lda + kb + c0 * 8, nxt + tid * 8);
            glds16(Ab + (long)r0 * lda + kb + c1 * 8, nxt + (tid + 256) * 8);
            glds16(Bb + (long)r0 * ldb + kb + c0 * 8, nxt + 4096 + tid * 8);
            glds16(Bb + (long)r0 * ldb + kb + c1 * 8, nxt + 4096 + (tid + 256) * 8);
            SYNC_VM4();   // oldest 4 (cur tile) landed; prefetch still in flight
        } else {
            SYNC_VM0();
        }
        bf16x8 af[4], bfr[4];
#pragma unroll
        for (int mi = 0; mi < 4; mi++)
            af[mi] = *(const bf16x8*)(cur + (q * 128 + wr + mi * 16 + l15) * 8);
#pragma unroll
        for (int ni = 0; ni < 4; ni++)
            bfr[ni] = *(const bf16x8*)(cur + 4096 + (q * 128 + wc + ni * 16 + l15) * 8);
#pragma unroll
        for (int mi = 0; mi < 4; mi++)
#pragma unroll
            for (int ni = 0; ni < 4; ni++)
                acc[mi][ni] = __builtin_amdgcn_mfma_f32_16x16x32_bf16(
                    af[mi], bfr[ni], acc[mi][ni], 0, 0, 0);
        SYNC_LGKM();  // all waves done reading cur -> next iter may overwrite it
    }

    // Epilogue. C/D layout: col = lane&15, row = (lane>>4)*4 + reg (m89).
    const float* sqb = (EPI != EBRELU) ? (sq + (long)bz * NP) : nullptr;
#pragma unroll
    for (int mi = 0; mi < 4; mi++) {
#pragma unroll
        for (int rg = 0; rg < 4; rg++) {
            const int grow = rowBase + wr + mi * 16 + q * 4 + rg;
            float rsumv = 0.f;
            float di = 0.f;
            if (EPI == ELAP1 || EPI == ELAP2) di = sqb[grow];
#pragma unroll
            for (int ni = 0; ni < 4; ni++) {
                const int gcol = colBase + wc + ni * 16 + l15;
                float v = acc[mi][ni][rg];
                long cidx = (long)bz * sC + (long)grow * ldc + gcol;
                if (EPI == EADJ) {
                    float e = __expf(2.f * v - sqb[grow] - sqb[gcol]);
                    C[cidx] = f2b(e);
                    rsumv += e;
                } else if (EPI == ELAP1) {
                    // X1 = out - D*(A*(D*out))
                    float o = b2f(aux[(long)bz * sAux + (long)grow * ldaux + gcol]);
                    C[cidx] = f2b(o - di * v);
                } else if (EPI == ELAP2) {
                    // X2 = 2*(X1 - D*(A*(D*X1))) - out
                    long abase = (long)bz * sAux + (long)grow * ldaux + gcol;
                    float o0 = b2f(aux[abase]);          // out  (cat block0)
                    float o1 = b2f(aux[abase + 1024]);   // X1   (cat block1)
                    C[cidx] = f2b(2.f * (o1 - di * v) - o0);
                } else {  // EBRELU
                    float bv = (gcol < biasN) ? bias[gcol] : 0.f;
                    float o = v + bv;
                    C[cidx] = f2b(o > 0.f ? o : 0.f);
                }
            }
            if (EPI == EADJ) {
                rsumv += __shfl_xor(rsumv, 1);
                rsumv += __shfl_xor(rsumv, 2);
                rsumv += __shfl_xor(rsumv, 4);
                rsumv += __shfl_xor(rsumv, 8);
                if (l15 == 0) atomicAdd(&rowsum[(long)bz * NP + grow], rsumv);
            }
        }
    }
}

// ---------------------------------------------------------------------------
// Scaled bf16 transpose: dst[c][r] = dv[r] * src[r][c]; grid (cols/64, rows/64, C)
// ---------------------------------------------------------------------------
__global__ __launch_bounds__(256) void k_trs(
    const unsigned short* __restrict__ src, long sS, int ldS,
    const float* __restrict__ dv,
    unsigned short* __restrict__ dst, long sD, int ldD)
{
    __shared__ unsigned short t[64][72];
    const int b = blockIdx.z;
    const int c0 = blockIdx.x * 64, r0 = blockIdx.y * 64;
    const unsigned short* S = src + (long)b * sS;
    const float* dvb = dv + (long)b * NP;
    unsigned short* D = dst + (long)b * sD;
    const int tx = threadIdx.x & 7, ty = threadIdx.x >> 3;
#pragma unroll
    for (int p = 0; p < 2; p++) {
        int r = ty + p * 32;
        float s = dvb[r0 + r];
        u16x8 v = *(const u16x8*)(S + (long)(r0 + r) * ldS + c0 + tx * 8);
#pragma unroll
        for (int k = 0; k < 8; k++) t[tx * 8 + k][r] = f2b(s * b2f(v[k]));
    }
    __syncthreads();
#pragma unroll
    for (int p = 0; p < 2; p++) {
        int r = ty + p * 32;
        u16x8 v;
#pragma unroll
        for (int k = 0; k < 8; k++) v[k] = t[r][tx * 8 + k];
        *(u16x8*)(D + (long)(c0 + r) * ldD + r0 + tx * 8) = v;
    }
}

// fp32 tiled transpose: dst[c*R + r] = src[r*C + c].  grid (ceil(C/32), ceil(R/32)),
// block dim3(32,8).
__global__ void k_trf32(const float* __restrict__ src, int R, int C,
                        float* __restrict__ dst)
{
    __shared__ float t[32][33];
    const int c0 = blockIdx.x * 32, r0 = blockIdx.y * 32;
#pragma unroll
    for (int p = 0; p < 4; p++) {
        int r = r0 + threadIdx.y + p * 8;
        int c = c0 + threadIdx.x;
        t[threadIdx.y + p * 8][threadIdx.x] =
            (r < R && c < C) ? src[(long)r * C + c] : 0.f;
    }
    __syncthreads();
#pragma unroll
    for (int p = 0; p < 4; p++) {
        int c = c0 + threadIdx.y + p * 8;   // dst row
        int r = r0 + threadIdx.x;           // dst col
        if (c < C && r < R) dst[(long)c * R + r] = t[threadIdx.x][threadIdx.y + p * 8];
    }
}

// ---------------------------------------------------------------------------
// Permuted+transposed weight fill: dst[o][s*FP+f] = W[(f*KK+s)*1000+o], 0-pad.
// grid (16, dstld/64), 256 thr.
// ---------------------------------------------------------------------------
__global__ __launch_bounds__(256) void k_wperm(
    const float* __restrict__ W, unsigned short* __restrict__ dst, int KK, int dstld)
{
    __shared__ float tile[64][65];
    const int o0 = blockIdx.x * 64;
    const int kk0 = blockIdx.y * 64;
    const int s = kk0 >> 10;
    const int fbase = kk0 & 1023;
    const int ci = threadIdx.x & 63;
    const int ri = threadIdx.x >> 6;
#pragma unroll 4
    for (int p = 0; p < 16; p++) {
        int fi = fbase + ri + p * 4;
        int oi = o0 + ci;
        float v = 0.f;
        if (fi < 1000 && oi < 1000) v = W[((long)fi * KK + s) * 1000 + oi];
        tile[ri + p * 4][ci] = v;
    }
    __syncthreads();
#pragma unroll 4
    for (int p = 0; p < 16; p++) {
        int orow = ri + p * 4;
        dst[(long)(o0 + orow) * dstld + kk0 + ci] = f2b(tile[ci][orow]);
    }
}

// zero-init of accumulators + catr pad rows + vr (for atomicMax).
__global__ void k_zinit(float* __restrict__ rs2, float* __restrict__ g,
                        float* __restrict__ racc, unsigned short* __restrict__ catrpad,
                        float* __restrict__ dv1, float* __restrict__ xacc1,
                        float* __restrict__ xacc2, float* __restrict__ yacc1,
                        float* __restrict__ yacc2, float* __restrict__ l2acc,
                        float* __restrict__ vr)
{
    long i = (long)blockIdx.x * 256 + threadIdx.x;
    if (i < (long)BB * NP) { rs2[i] = 0.f; dv1[i] = 0.f; }
    if (i < (long)BB * FP) g[i] = 0.f;
    if (i < 64) racc[i] = 0.f;
    if (i < (long)(MRp - 320) * RK) catrpad[i] = 0;
    if (i < (long)BB * 6 * NP) { xacc1[i] = 0.f; xacc2[i] = 0.f; l2acc[i] = 0.f; }
    if (i < (long)BB * 6 * FP) { yacc1[i] = 0.f; yacc2[i] = 0.f; }
    if (i < (long)BB * RR * FP) vr[i] = 0.f;
}

// x (B,N,6) -> x6t (B,6,N) + sqx (B,N).  grid (8, BB)
__global__ void k_xprep(const float* __restrict__ x, float* __restrict__ x6t,
                        float* __restrict__ sqx)
{
    const int b = blockIdx.y;
    const int j = blockIdx.x * 256 + threadIdx.x;
    float s = 0.f;
#pragma unroll
    for (int c = 0; c < 6; c++) {
        float v = x[((long)b * NP + j) * 6 + c];
        x6t[(long)b * 6 * NP + c * NP + j] = v;
        s += v * v;
    }
    sqx[(long)b * NP + j] = s;
}

// x-graph laplacian passes, j-split across NJ chunks with atomic reduction.
// grid (8, NJ, BB), block 256.
template <int MODE>
__global__ __launch_bounds__(256) void k_lapj(
    const float* __restrict__ x6t, const float* __restrict__ sqx,
    const float* __restrict__ dv1, const float* __restrict__ srct,
    float* __restrict__ acc)
{
    const int b = blockIdx.z;
    const int row = blockIdx.x * 256 + threadIdx.x;
    const int j0 = blockIdx.y * (NP / NJ);
    const float* xt = x6t + (long)b * 6 * NP;
    const float* sq = sqx + (long)b * NP;
    float xi[6];
#pragma unroll
    for (int c = 0; c < 6; c++) xi[c] = xt[c * NP + row];
    const float sqi = sq[row];
    const float* dv = (MODE >= 1) ? (dv1 + (long)b * NP) : nullptr;
    const float* st = (MODE >= 1) ? (srct + (long)b * 6 * NP) : nullptr;
    float s0 = 0.f;
    float sc[6] = {0, 0, 0, 0, 0, 0};
    for (int j = j0; j < j0 + NP / NJ; j++) {
        float dot = 0.f;
#pragma unroll
        for (int c = 0; c < 6; c++) dot += xi[c] * xt[c * NP + j];
        float e = __expf(2.f * dot - sqi - sq[j]);
        if (MODE == 0) {
            s0 += e;
        } else {
            float wgt = e * dv[j];
#pragma unroll
            for (int c = 0; c < 6; c++) sc[c] += wgt * st[c * NP + j];
        }
    }
    if (MODE == 0) {
        atomicAdd(&acc[(long)b * NP + row], s0);
    } else {
#pragma unroll
        for (int c = 0; c < 6; c++)
            atomicAdd(&acc[(long)b * 6 * NP + c * NP + row], sc[c]);
    }
}

// finalize lap pass: MODE 1: out = xi - di*sc ; MODE 2: out = 2*(x1-di*sc)-xi
// grid (8, B') block 256
template <int MODE>
__global__ void k_lfin(const float* __restrict__ x6t, const float* __restrict__ dv1,
                       const float* __restrict__ xacc, const float* __restrict__ x1t6,
                       float* __restrict__ outv)
{
    const int b = blockIdx.y;
    const int row = blockIdx.x * 256 + threadIdx.x;
    const float di = dv1[(long)b * NP + row];
#pragma unroll
    for (int c = 0; c < 6; c++) {
        long idx = (long)b * 6 * NP + c * NP + row;
        float xi = x6t[idx];
        float sc = xacc[idx];
        if (MODE == 1) outv[idx] = xi - di * sc;
        else           outv[idx] = 2.f * (x1t6[idx] - di * sc) - xi;
    }
}

// adjx: l2acc[b,c,row] += sum_{j in chunk} adj[row][j] * dv[j] * x6t[c][j]
// grid (NP/64, NJ2, C), block 256 (64 rows x 4 lanes).
__global__ __launch_bounds__(256) void k_adjx(
    const unsigned short* __restrict__ adj, const float* __restrict__ dv,
    const float* __restrict__ x6t, float* __restrict__ l2acc)
{
    __shared__ float xs[6][256];
    __shared__ float dvs[256];
    __shared__ float lsum[64][4][6];
    const int b = blockIdx.z;
    const int j0 = blockIdx.y * (NP / NJ2);   // 256-col chunk
    if (threadIdx.x < 256) dvs[threadIdx.x] = dv[(long)b * NP + j0 + threadIdx.x];
    for (int e = threadIdx.x; e < 6 * 256; e += 256) {
        int c = e >> 8, j = e & 255;
        xs[c][j] = x6t[(long)b * 6 * NP + c * NP + j0 + j];
    }
    __syncthreads();
    const int ty = threadIdx.x >> 2;
    const int tx = threadIdx.x & 3;
    const int grow = blockIdx.x * 64 + ty;
    const unsigned short* rowp = adj + (long)b * NP * NP + (long)grow * NP + j0;
    float sc[6] = {0, 0, 0, 0, 0, 0};
    for (int it = 0; it < 8; it++) {
        int col = it * 32 + tx * 8;
        u16x8 a8 = *(const u16x8*)(rowp + col);
#pragma unroll
        for (int k = 0; k < 8; k++) {
            float w = b2f(a8[k]) * dvs[col + k];
#pragma unroll
            for (int c = 0; c < 6; c++) sc[c] += w * xs[c][col + k];
        }
    }
#pragma unroll
    for (int c = 0; c < 6; c++) lsum[ty][tx][c] = sc[c];
    __syncthreads();
    for (int e = threadIdx.x; e < 64 * 6; e += 256) {
        int row = e / 6, c = e % 6;
        float t = lsum[row][0][c] + lsum[row][1][c] + lsum[row][2][c] + lsum[row][3][c];
        atomicAdd(&l2acc[(long)b * 6 * NP + (long)c * NP + blockIdx.x * 64 + row], t);
    }
}

// cheb1: out = relu([x|x1|x2]_interleaved @ W1 + b1) -> cat block0 (bf16, pad 0)
// grid (16 ntile, 4 ftile, C)
__global__ __launch_bounds__(256) void k_cheb1(
    const float* __restrict__ x, const float* __restrict__ x1t6,
    const float* __restrict__ x2t6, const float* __restrict__ W1,
    const float* __restrict__ b1, unsigned short* __restrict__ cat)
{
    __shared__ float xk[128 * 18];
    const int b = blockIdx.z;
    const int n0 = blockIdx.x * 128;
    const int f0 = blockIdx.y * 256;
    for (int e = threadIdx.x; e < 128 * 18; e += 256) {
        int rown = e / 18, c18 = e % 18;
        int cc = c18 / 3, kk = c18 % 3;
        int n = n0 + rown;
        float v;
        if (kk == 0) v = x[((long)b * NP + n) * 6 + cc];
        else if (kk == 1) v = x1t6[(long)b * 6 * NP + cc * NP + n];
        else v = x2t6[(long)b * 6 * NP + cc * NP + n];
        xk[e] = v;
    }
    __syncthreads();
    for (int gi = threadIdx.x; gi < 128 * 64; gi += 256) {
        int rown = gi >> 6;
        int f4 = f0 + (gi & 63) * 4;
        float a0 = 0, a1 = 0, a2 = 0, a3 = 0;
        if (f4 < 1000) {
            a0 = b1[f4]; a1 = b1[f4 + 1]; a2 = b1[f4 + 2]; a3 = b1[f4 + 3];
#pragma unroll
            for (int cI = 0; cI < 18; cI++) {
                float xv = xk[rown * 18 + cI];
                f32x4 w = *(const f32x4*)(W1 + cI * 1000 + f4);
                a0 += xv * w[0]; a1 += xv * w[1]; a2 += xv * w[2]; a3 += xv * w[3];
            }
            a0 = a0 > 0 ? a0 : 0; a1 = a1 > 0 ? a1 : 0;
            a2 = a2 > 0 ? a2 : 0; a3 = a3 > 0 ? a3 : 0;
        }
        u16x4 o;
        o[0] = f2b(a0); o[1] = f2b(a1); o[2] = f2b(a2); o[3] = f2b(a3);
        *(u16x4*)(cat + (long)b * NP * K3 + (long)(n0 + rown) * K3 + f4) = o;
    }
}

// sqc[b,i] = sum_f bf16(out)[b,i,f]^2   grid (NP/16, C)
__global__ void k_sqc(const unsigned short* __restrict__ cat, float* __restrict__ sqc)
{
    __shared__ float red[256];
    const int b = blockIdx.y;
    const int rloc = threadIdx.x >> 4;
    const int r = blockIdx.x * 16 + rloc;
    const int tx = threadIdx.x & 15;
    const unsigned short* p = cat + (long)b * NP * K3 + (long)r * K3;
    float s = 0.f;
    for (int it = 0; it < 8; it++) {
        int cc = it * 128 + tx * 8;
        u16x8 v = *(const u16x8*)(p + cc);
#pragma unroll
        for (int k = 0; k < 8; k++) { float f = b2f(v[k]); s += f * f; }
    }
    red[threadIdx.x] = s;
    __syncthreads();
    if (tx == 0) {
        float t = 0.f;
#pragma unroll
        for (int k = 0; k < 16; k++) t += red[rloc * 16 + k];
        sqc[(long)b * NP + r] = t;
    }
}

__global__ void k_rsqrt(float* __restrict__ p) {
    int i = blockIdx.x * 256 + threadIdx.x;
    p[i] = rsqrtf(p[i]);
}

// vertices_Reeb: vr[b,r,f] = max_g out[b,sccs[b,r,g],f].  grid (RR, C, 4 gchunk).
// fp32-as-int atomicMax valid: relu outputs >= 0; vr zero-init.
__global__ void k_vr(const unsigned short* __restrict__ cat,
                     const int* __restrict__ sccs, float* __restrict__ vr)
{
    const int b = blockIdx.y, r = blockIdx.x;
    const int g0 = blockIdx.z * (GG / 4);
    const int f4 = threadIdx.x * 4;
    const int* sp = sccs + ((long)b * RR + r) * GG;
    float m0 = 0.f, m1 = 0.f, m2 = 0.f, m3 = 0.f;
    for (int g = g0; g < g0 + GG / 4; g++) {
        int idx = sp[g];
        u16x4 v = *(const u16x4*)(cat + ((long)b * NP + idx) * K3 + f4);
        m0 = fmaxf(m0, b2f(v[0])); m1 = fmaxf(m1, b2f(v[1]));
        m2 = fmaxf(m2, b2f(v[2])); m3 = fmaxf(m3, b2f(v[3]));
    }
    float* op = vr + ((long)b * RR + r) * FP + f4;
    atomicMax((int*)&op[0], __float_as_int(m0));
    atomicMax((int*)&op[1], __float_as_int(m1));
    atomicMax((int*)&op[2], __float_as_int(m2));
    atomicMax((int*)&op[3], __float_as_int(m3));
}

// Reeb Chebyshev recursion (fp32), f-parallel. grid (4, BB), one f per thread.
__global__ __launch_bounds__(256) void k_reeb(
    const float* __restrict__ vr, const float* __restrict__ lapR,
    unsigned short* __restrict__ catr)
{
    __shared__ float Lr[RR * RR];
    const int b = blockIdx.y;
    for (int e = threadIdx.x; e < RR * RR; e += 256) Lr[e] = lapR[(long)b * RR * RR + e];
    __syncthreads();
    const int f = blockIdx.x * 256 + threadIdx.x;
    float xa[RR], xb[RR], xc[RR];
#pragma unroll
    for (int r = 0; r < RR; r++) xa[r] = vr[((long)b * RR + r) * FP + f];
#pragma unroll
    for (int r = 0; r < RR; r++) catr[((long)b * RR + r) * RK + f] = f2b(xa[r]);
#pragma unroll
    for (int r = 0; r < RR; r++) {
        float s = 0.f;
#pragma unroll
        for (int qq = 0; qq < RR; qq++) s += Lr[r * RR + qq] * xa[qq];
        xb[r] = s;
    }
#pragma unroll
    for (int r = 0; r < RR; r++) catr[((long)b * RR + r) * RK + FP + f] = f2b(xb[r]);
    for (int st = 2; st < 6; st++) {
#pragma unroll
        for (int r = 0; r < RR; r++) {
            float s = 0.f;
#pragma unroll
            for (int qq = 0; qq < RR; qq++) s += Lr[r * RR + qq] * xb[qq];
            xc[r] = 2.f * s - xa[r];
        }
#pragma unroll
        for (int r = 0; r < RR; r++)
            catr[((long)b * RR + r) * RK + st * FP + f] = f2b(xc[r]);
#pragma unroll
        for (int r = 0; r < RR; r++) { xa[r] = xb[r]; xb[r] = xc[r]; }
    }
}

// g[b,f] = max_n out2[b,n,f]  (int atomicMax; relu values >= 0, g pre-zeroed)
__global__ void k_gmax(const unsigned short* __restrict__ out2, float* __restrict__ g)
{  // grid (4, 8, C)
    const int b = blockIdx.z;
    const int f = blockIdx.x * 256 + threadIdx.x;
    const int n0 = blockIdx.y * 256;
    float m = 0.f;
    for (int n = n0; n < n0 + 256; n++)
        m = fmaxf(m, b2f(out2[((long)b * NP + n) * FP + f]));
    if (f < 1000) atomicMax((int*)&g[(long)b * FP + f], __float_as_int(m));
}

__global__ void k_grmax(const unsigned short* __restrict__ outr, float* __restrict__ gr)
{  // grid (4, BB)
    const int b = blockIdx.y;
    const int f = blockIdx.x * 256 + threadIdx.x;
    float m = -1e30f;
    for (int r = 0; r < RR; r++)
        m = fmaxf(m, b2f(outr[((long)b * RR + r) * FP + f]));
    gr[(long)b * FP + f] = (f < 1000) ? m : 0.f;
}

// rnorm stage 1: yacc[b,c,f] += sum_{i in chunk} mat[b,i,f] * v6[b,c,i]
// grid (4 fblk, NI, C) block 256
__global__ __launch_bounds__(256) void k_rnacc(
    const unsigned short* __restrict__ mat, long sM, int ldm,
    const float* __restrict__ vt6, float* __restrict__ yacc)
{
    const int b = blockIdx.z;
    const int f = blockIdx.x * 256 + threadIdx.x;
    const int i0 = blockIdx.y * (NP / NI);
    const unsigned short* mp = mat + (long)b * sM + f;
    const float* vp = vt6 + (long)b * 6 * NP;
    float a[6] = {0, 0, 0, 0, 0, 0};
    for (int i = i0; i < i0 + NP / NI; i++) {
        float o = b2f(mp[(long)i * ldm]);
#pragma unroll
        for (int c = 0; c < 6; c++) a[c] += o * vp[c * NP + i];
    }
#pragma unroll
    for (int c = 0; c < 6; c++)
        atomicAdd(&yacc[((long)b * 6 + c) * FP + f], a[c]);
}

// rnorm stage 2: racc[bi] += partial sum of yacc^2.  grid (2, 16) block 256
__global__ void k_rnred(const float* __restrict__ yacc1,
                        const float* __restrict__ yacc2, float* __restrict__ racc)
{
    __shared__ float red[256];
    const float* y = (blockIdx.x == 0) ? yacc1 : yacc2;
    const long tot = (long)BB * 6 * FP;
    const long per = tot / 16;
    const long e0 = blockIdx.y * per;
    float s = 0.f;
    for (long e = e0 + threadIdx.x; e < e0 + per; e += 256) {
        float v = y[e];
        s += v * v;
    }
    red[threadIdx.x] = s;
    __syncthreads();
    for (int st = 128; st > 0; st >>= 1) {
        if (threadIdx.x < st) red[threadIdx.x] += red[threadIdx.x + st];
        __syncthreads();
    }
    if (threadIdx.x == 0) atomicAdd(&racc[blockIdx.x], red[0]);
}

// h1 = relu([gR|g] @ Wfc1 + bfc1), wave-per-output with WT1 (512 x 2000).
// grid (128, BB) block 256 (4 waves)
__global__ __launch_bounds__(256) void k_fc1w(
    const float* __restrict__ gr, const float* __restrict__ g,
    const float* __restrict__ WT1, const float* __restrict__ bias,
    float* __restrict__ h1)
{
    const int b = blockIdx.y;
    const int lane = threadIdx.x & 63;
    const int o = blockIdx.x * 4 + (threadIdx.x >> 6);
    const float* wt = WT1 + (long)o * 2000;
    const float* grp = gr + (long)b * FP;
    const float* gp = g + (long)b * FP;
    float s = 0.f;
    for (int j0 = 0; j0 < 2000; j0 += 64) {
        int j = j0 + lane;
        if (j < 2000) {
            float fv = (j < 1000) ? grp[j] : gp[j - 1000];
            s += fv * wt[j];
        }
    }
#pragma unroll
    for (int d = 1; d < 64; d <<= 1) s += __shfl_xor(s, d);
    if (lane == 0) {
        float v = s + bias[o];
        h1[(long)b * 512 + o] = v > 0.f ? v : 0.f;
    }
}

// h2 = relu(h1 @ Wfc2 + bfc2), wave-per-output with WT2 (128 x 512).
// grid (32, BB) block 256
__global__ __launch_bounds__(256) void k_fc2w(
    const float* __restrict__ h1, const float* __restrict__ WT2,
    const float* __restrict__ bias, float* __restrict__ h2)
{
    const int b = blockIdx.y;
    const int lane = threadIdx.x & 63;
    const int o = blockIdx.x * 4 + (threadIdx.x >> 6);
    const float* wt = WT2 + (long)o * 512;
    const float* hp = h1 + (long)b * 512;
    float s = 0.f;
#pragma unroll
    for (int j0 = 0; j0 < 512; j0 += 64) s += hp[j0 + lane] * wt[j0 + lane];
#pragma unroll
    for (int d = 1; d < 64; d <<= 1) s += __shfl_xor(s, d);
    if (lane == 0) {
        float v = s + bias[o];
        h2[(long)b * 128 + o] = v > 0.f ? v : 0.f;
    }
}

// final FC + regs.  grid(4) block 256: blk0=FC3, blk1/2/3 = weight-norm sums.
__global__ void k_tail(const float* __restrict__ h2, const float* __restrict__ Wfc3,
                       const float* __restrict__ bfc3, const float* __restrict__ Wfc1,
                       const float* __restrict__ bfc1, const float* __restrict__ Wfc2,
                       const float* __restrict__ bfc2, const float* __restrict__ racc,
                       float* __restrict__ out)
{
    if (blockIdx.x == 0) {
        for (int e = threadIdx.x; e < 640; e += 256) {
            int row = e / 40, o = e % 40;
            float s = bfc3[o];
            for (int j = 0; j < 128; j++) s += h2[row * 128 + j] * Wfc3[j * 40 + o];
            out[e] = s;
        }
        return;
    }
    __shared__ float red[256];
    float s = 0.f;
    if (blockIdx.x == 1) {
        for (int j = threadIdx.x; j < 2000; j += 256) { float w = Wfc1[j * 512]; s += w * w; }
    } else if (blockIdx.x == 2) {
        for (int j = threadIdx.x; j < 512; j += 256) { float w = Wfc2[j * 128]; s += w * w; }
    } else {
        for (int j = threadIdx.x; j < 128; j += 256) { float w = Wfc3[j * 40]; s += w * w; }
    }
    red[threadIdx.x] = s;
    __syncthreads();
    for (int st = 128; st > 0; st >>= 1) {
        if (threadIdx.x < st) red[threadIdx.x] += red[threadIdx.x + st];
        __syncthreads();
    }
    if (threadIdx.x == 0) {
        if (blockIdx.x == 1) out[642] = red[0];
        else if (blockIdx.x == 2) out[644] = red[0];
        else {
            out[646] = red[0];
            out[640] = sqrtf(racc[0]);
            out[641] = sqrtf(racc[1]);
            out[643] = bfc1[0] * bfc1[0];
            out[645] = bfc2[0] * bfc2[0];
            out[647] = bfc3[0] * bfc3[0];
        }
    }
}

// ---------------------------------------------------------------------------
extern "C" void kernel_launch(void* const* d_in, const int* in_sizes, int n_in,
                              void* d_out, int out_size, void* d_ws, size_t ws_size,
                              hipStream_t stream)
{
    (void)in_sizes; (void)n_in; (void)out_size;
    const float* x    = (const float*)d_in[0];
    const float* lapR = (const float*)d_in[1];
    const int*   sccs = (const int*)d_in[2];
    const float* W1   = (const float*)d_in[3];
    const float* b1   = (const float*)d_in[4];
    const float* W2   = (const float*)d_in[5];
    const float* b2   = (const float*)d_in[6];
    const float* Wr   = (const float*)d_in[7];
    const float* br   = (const float*)d_in[8];
    const float* Wfc1 = (const float*)d_in[9];
    const float* bfc1 = (const float*)d_in[10];
    const float* Wfc2 = (const float*)d_in[11];
    const float* bfc2 = (const float*)d_in[12];
    const float* Wfc3 = (const float*)d_in[13];
    const float* bfc3 = (const float*)d_in[14];
    float* out = (float*)d_out;

    char* w = (char*)d_ws;
    size_t used = 0;
    auto alloc = [&](size_t bytes) {
        char* p = w + used;
        used += (bytes + 255) & ~(size_t)255;
        return p;
    };
    // ---- persistent buffers (~37 MB) ----
    unsigned short* w2pt = (unsigned short*)alloc((size_t)FP * K3 * 2);
    unsigned short* wrpt = (unsigned short*)alloc((size_t)FP * RK * 2);
    unsigned short* catr = (unsigned short*)alloc((size_t)MRp * RK * 2);
    unsigned short* outr = (unsigned short*)alloc((size_t)MRp * FP * 2);
    float* vr   = (float*)alloc((size_t)BB * RR * FP * 4);
    float* x6t  = (float*)alloc((size_t)BB * 6 * NP * 4);
    float* sqx  = (float*)alloc((size_t)BB * NP * 4);
    float* dv1  = (float*)alloc((size_t)BB * NP * 4);
    float* x1t6 = (float*)alloc((size_t)BB * 6 * NP * 4);
    float* x2t6 = (float*)alloc((size_t)BB * 6 * NP * 4);
    float* xacc1= (float*)alloc((size_t)BB * 6 * NP * 4);
    float* xacc2= (float*)alloc((size_t)BB * 6 * NP * 4);
    float* l2acc= (float*)alloc((size_t)BB * 6 * NP * 4);
    float* sqc  = (float*)alloc((size_t)BB * NP * 4);
    float* rs2  = (float*)alloc((size_t)BB * NP * 4);
    float* l2xt6= (float*)alloc((size_t)BB * 6 * NP * 4);
    float* g    = (float*)alloc((size_t)BB * FP * 4);
    float* gr   = (float*)alloc((size_t)BB * FP * 4);
    float* h1   = (float*)alloc((size_t)BB * 512 * 4);
    float* h2   = (float*)alloc((size_t)BB * 128 * 4);
    float* racc = (float*)alloc(256);
    float* WT1  = (float*)alloc((size_t)512 * 2000 * 4);
    float* WT2  = (float*)alloc((size_t)128 * 512 * 4);
    float* yacc1= (float*)alloc((size_t)BB * 6 * FP * 4);
    float* yacc2= (float*)alloc((size_t)BB * 6 * FP * 4);

    // ---- choose batch chunk size C so chunk buffers fit ws ----
    const size_t PCAT = (size_t)NP * K3 * 2;   // 12.58 MB / batch
    const size_t PA   = (size_t)NP * NP * 2;   //  8.39 MB / batch (adj; out2 aliases)
    const size_t PTT  = (size_t)FP * NP * 2;   //  4.19 MB / batch
    int C = 16;
    while (C > 1 && used + (size_t)C * (PCAT + PA + PTT) + 4096 > ws_size) C >>= 1;
    if (used + (size_t)C * (PCAT + PA + PTT) + 4096 > ws_size) return;  // ws too small

    unsigned short* cat_c = (unsigned short*)alloc((size_t)C * PCAT);
    unsigned short* a_c   = (unsigned short*)alloc((size_t)C * PA);
    unsigned short* tt_c  = (unsigned short*)alloc((size_t)C * PTT);
    unsigned short* out2_c = a_c;  // alias: adj dead once G4 runs

    const long sCat = (long)NP * K3;
    const long sL2  = (long)NP * NP;
    const long sTT  = (long)FP * NP;
    const long sO2  = (long)NP * FP;

    // zero inits (ws is re-poisoned to 0xAA before every timed call)
    k_zinit<<<dim3(1536), 256, 0, stream>>>(rs2, g, racc, catr + (size_t)320 * RK,
                                            dv1, xacc1, xacc2, yacc1, yacc2, l2acc, vr);

    // weight prep
    k_wperm<<<dim3(16, K3 / 64), 256, 0, stream>>>(W2, w2pt, 3, K3);
    k_wperm<<<dim3(16, RK / 64), 256, 0, stream>>>(Wr, wrpt, 6, RK);
    k_trf32<<<dim3(16, 63), dim3(32, 8), 0, stream>>>(Wfc1, 2000, 512, WT1);
    k_trf32<<<dim3(4, 16), dim3(32, 8), 0, stream>>>(Wfc2, 512, 128, WT2);

    // x-graph laplacian path (fp32, full batch, j-split + atomic reduce)
    k_xprep<<<dim3(8, BB), 256, 0, stream>>>(x, x6t, sqx);
    k_lapj<0><<<dim3(8, NJ, BB), 256, 0, stream>>>(x6t, sqx, nullptr, nullptr, dv1);
    k_rsqrt<<<dim3(BB * NP / 256), 256, 0, stream>>>(dv1);
    k_lapj<1><<<dim3(8, NJ, BB), 256, 0, stream>>>(x6t, sqx, dv1, x6t, xacc1);
    k_lfin<1><<<dim3(8, BB), 256, 0, stream>>>(x6t, dv1, xacc1, nullptr, x1t6);
    k_lapj<2><<<dim3(8, NJ, BB), 256, 0, stream>>>(x6t, sqx, dv1, x1t6, xacc2);
    k_lfin<2><<<dim3(8, BB), 256, 0, stream>>>(x6t, dv1, xacc2, x1t6, x2t6);

    for (int c0 = 0; c0 < BB; c0 += C) {
        const float* xc  = x     + (long)c0 * NP * 6;
        const float* x6c = x6t   + (long)c0 * 6 * NP;
        const float* x1c = x1t6  + (long)c0 * 6 * NP;
        const float* x2c = x2t6  + (long)c0 * 6 * NP;
        float*       sqcc= sqc   + (long)c0 * NP;
        float*       rsc = rs2   + (long)c0 * NP;
        float*       l2ac= l2acc + (long)c0 * 6 * NP;
        float*       l2xc= l2xt6 + (long)c0 * 6 * NP;

        // cheb1 -> cat block0 (out, bf16); sqc
        k_cheb1<<<dim3(16, 4, C), 256, 0, stream>>>(xc, x1c, x2c, W1, b1, cat_c);
        k_sqc<<<dim3(NP / 16, C), 256, 0, stream>>>(cat_c, sqcc);

        // G1: adj = exp(2*out@out^T - sq_i - sq_j), rowsums -> rsc; dv = rsqrt
        gemm_bt<EADJ><<<dim3(16, 16, C), 256, 0, stream>>>(
            cat_c, sCat, K3, cat_c, sCat, K3, a_c, sL2, NP, FP,
            sqcc, rsc, nullptr, 0, 0, nullptr, 0);
        k_rsqrt<<<dim3(C * NP / 256), 256, 0, stream>>>(rsc);

        // L2@x for reg-norm: l2x = x - D*(A*(D*x))   (reads adj once, no write-back)
        k_adjx<<<dim3(NP / 64, NJ2, C), 256, 0, stream>>>(a_c, rsc, x6c, l2ac);
        k_lfin<1><<<dim3(8, C), 256, 0, stream>>>(x6c, rsc, l2ac, nullptr, l2xc);

        // G2: X1 = out - D*(A*(D*out))  (B = (D*out)^T via scaled transpose)
        k_trs<<<dim3(16, 32, C), 256, 0, stream>>>(cat_c, sCat, K3, rsc, tt_c, sTT, NP);
        gemm_bt<ELAP1><<<dim3(8, 16, C), 256, 0, stream>>>(
            a_c, sL2, NP, tt_c, sTT, NP, cat_c + 1024, sCat, K3, NP,
            rsc, nullptr, cat_c, sCat, K3, nullptr, 0);

        // G3: X2 = 2*(X1 - D*(A*(D*X1))) - out
        k_trs<<<dim3(16, 32, C), 256, 0, stream>>>(cat_c + 1024, sCat, K3, rsc, tt_c, sTT, NP);
        gemm_bt<ELAP2><<<dim3(8, 16, C), 256, 0, stream>>>(
            a_c, sL2, NP, tt_c, sTT, NP, cat_c + 2048, sCat, K3, NP,
            rsc, nullptr, cat_c, sCat, K3, nullptr, 0);

        // G4: out2 = relu(cat @ W2perm^T + b2)   (out2 overwrites adj region)
        gemm_bt<EBRELU><<<dim3(8, 16, C), 256, 0, stream>>>(
            cat_c, sCat, K3, w2pt, 0, K3, out2_c, sO2, FP, K3,
            nullptr, nullptr, nullptr, 0, 0, b2, 1000);

        // pools + regs for this chunk
        k_vr<<<dim3(RR, C, 4), 256, 0, stream>>>(
            cat_c, sccs + (long)c0 * RR * GG, vr + (long)c0 * RR * FP);
        k_gmax<<<dim3(4, 8, C), 256, 0, stream>>>(out2_c, g + (long)c0 * FP);
        k_rnacc<<<dim3(4, NI, C), 256, 0, stream>>>(
            cat_c, sCat, K3, x1c, yacc1 + (long)c0 * 6 * FP);
        k_rnacc<<<dim3(4, NI, C), 256, 0, stream>>>(
            out2_c, sO2, FP, l2xc, yacc2 + (long)c0 * 6 * FP);
    }

    // Reeb branch (full batch, f-parallel)
    k_reeb<<<dim3(4, BB), 256, 0, stream>>>(vr, lapR, catr);
    gemm_bt<EBRELU><<<dim3(8, 3, 1), 256, 0, stream>>>(
        catr, 0, RK, wrpt, 0, RK, outr, 0, FP, RK,
        nullptr, nullptr, nullptr, 0, 0, br, 1000);
    k_grmax<<<dim3(4, BB), 256, 0, stream>>>(outr, gr);

    // regs stage 2 + FC head
    k_rnred<<<dim3(2, 16), 256, 0, stream>>>(yacc1, yacc2, racc);
    k_fc1w<<<dim3(128, BB), 256, 0, stream>>>(gr, g, WT1, bfc1, h1);
    k_fc2w<<<dim3(32, BB), 256, 0, stream>>>(h1, WT2, bfc2, h2);
    k_tail<<<dim3(4), 256, 0, stream>>>(h2, Wfc3, bfc3, Wfc1, bfc1, Wfc2, bfc2, racc, out);
}

// Round 9
// 1955.240 us; speedup vs baseline: 1.7082x; 1.1428x over previous
//
#include <hip/hip_runtime.h>
#include <stdint.h>

#define DI __device__ __forceinline__

typedef __bf16 bf16x8 __attribute__((ext_vector_type(8)));
typedef float f32x4 __attribute__((ext_vector_type(4)));
typedef unsigned short u16x4 __attribute__((ext_vector_type(4)));
typedef unsigned short u16x8 __attribute__((ext_vector_type(8)));

static constexpr int BB = 16;     // batch
static constexpr int NP = 2048;   // points
static constexpr int FP = 1024;   // padded F1 (=1000)
static constexpr int K3 = 3072;   // 3*FP
static constexpr int RR = 20;     // Reeb nodes
static constexpr int GG = 128;    // group size
static constexpr int RK = 6144;   // 6*FP
static constexpr int MRp = 384;   // padded 16*20=320 -> 384
static constexpr int NJ = 32;     // j-chunks for lap passes
static constexpr int NI = 8;      // i-chunks for rnorm stage 1
static constexpr int NJ2 = 8;     // j-chunks for adjx
static constexpr int TPAD = 132;  // EADJ mirror tile pad (8-B aligned, 2-bank row step)

DI float b2f(unsigned short u) {
    unsigned v = ((unsigned)u) << 16;
    return __builtin_bit_cast(float, v);
}
DI unsigned short f2b(float f) {
    unsigned u = __builtin_bit_cast(unsigned, f);
    unsigned r = (u + 0x7FFFu + ((u >> 16) & 1u)) >> 16;
    return (unsigned short)r;
}

DI void glds16(const unsigned short* g, unsigned short* l) {
    __builtin_amdgcn_global_load_lds(
        (const __attribute__((address_space(1))) void*)g,
        (__attribute__((address_space(3))) void*)l, 16, 0, 0);
}

// Manual sync (CK-style): memory-clobber asm = compiler fence; explicit vmcnt
// avoids __syncthreads' vmcnt(0) drain of in-flight prefetches.
#define SYNC_VM4() asm volatile("s_waitcnt vmcnt(4)\n\ts_barrier" ::: "memory")
#define SYNC_VM0() asm volatile("s_waitcnt vmcnt(0)\n\ts_barrier" ::: "memory")
#define SYNC_LGKM() asm volatile("s_waitcnt lgkmcnt(0)\n\ts_barrier" ::: "memory")

// ---------------------------------------------------------------------------
// BT-form bf16 MFMA GEMM: C = A @ B^T, 128x128 tile, BK=32, double-buffered
// LDS (2 x 16 KB) with manual vmcnt(4) sync. 226 us / MfmaUtil 18.7% is this
// structure's plateau: triple-buffer (R6) neutral; no-LDS direct-register (R7)
// regressed to 374 us. Do not re-attempt those.
// EADJ: adj is SYMMETRIC -> triangle grid (136 tiles) + LDS-transposed mirror
// write + column-sum into rowsum. EACCR: split-K (blockIdx.z = k-chunk) with
// fp32 atomic accumulation (for the tiny 24-block Reeb gemm).
// XCD-pinned block swizzle for L2 locality (404->140 MB FETCH).
// ---------------------------------------------------------------------------
enum { EADJ = 0, ELAP1 = 1, ELAP2 = 2, EBRELU = 3, EACCR = 4 };

template <int EPI>
__global__ __launch_bounds__(256) void gemm_bt(
    const unsigned short* __restrict__ A, long sA, int lda,
    const unsigned short* __restrict__ Bt, long sB, int ldb,
    unsigned short* __restrict__ C, long sC, int ldc, int K,
    const float* __restrict__ sq,        // EADJ: sq norms; ELAP*: dv (per-batch NP)
    float* __restrict__ rowsum,          // EADJ: rowsums; EACCR: fp32 accum
    const unsigned short* __restrict__ aux, long sAux, int ldaux,  // ELAP1/2: cat
    const float* __restrict__ bias, int biasN)                     // EBRELU
{
    __shared__ unsigned short smem[128 * TPAD];  // >= 16384 K-loop shorts; EADJ mirror tile
    const int tid = threadIdx.x;

    // ---- XCD-pinned strip-mined swizzle ----
    int gx = gridDim.x, gy = gridDim.y;
    int flat = blockIdx.x + gx * (blockIdx.y + gy * blockIdx.z);
    int tpb = gx * gy;
    int T = tpb * gridDim.z;
    int bz, ty, tx;
    if (((T & 7) == 0) && ((gx & 7) == 0)) {
        int per = T >> 3;
        int g = (flat & 7) * per + (flat >> 3);
        bz = g / tpb;
        int t = g - bz * tpb;
        int strip = gy << 3;          // tiles per 8-wide col-group
        int cg = t / strip;
        int r = t - cg * strip;
        ty = r >> 3;
        tx = (cg << 3) + (r & 7);
    } else {
        bz = blockIdx.z; ty = blockIdx.y; tx = blockIdx.x;
    }
    bool diag = true;
    if (EPI == EADJ) {
        // grid (136, 1, C): tx = flat triangle index -> (ty<=tx) tile coords
        int t = tx;
        int qx = 0;
        while ((qx + 1) * (qx + 2) / 2 <= t) qx++;
        ty = t - qx * (qx + 1) / 2;
        tx = qx;
        diag = (ty == tx);
    }
    const int rowBase = ty * 128;
    const int colBase = tx * 128;
    const unsigned short* Ab;
    const unsigned short* Bb;
    if (EPI == EACCR) {
        // bz = k-chunk index; batch stride unused (single logical batch)
        Ab = A + (long)rowBase * lda + (long)bz * K;
        Bb = Bt + (long)colBase * ldb + (long)bz * K;
    } else {
        Ab = A + (long)bz * sA + (long)rowBase * lda;
        Bb = Bt + (long)bz * sB + (long)colBase * ldb;
    }

    const int lane = tid & 63;
    const int q = lane >> 4;
    const int l15 = lane & 15;
    const int wave = tid >> 6;
    const int wr = (wave >> 1) * 64;
    const int wc = (wave & 1) * 64;

    const int r0 = tid & 127, c0 = tid >> 7;  // staging chunk (row, col8)
    const int c1 = c0 + 2;

    f32x4 acc[4][4];
#pragma unroll
    for (int i = 0; i < 4; i++)
#pragma unroll
        for (int j = 0; j < 4; j++) acc[i][j] = f32x4{0.f, 0.f, 0.f, 0.f};

    const int nIter = K >> 5;
    // prologue: stage tile 0 into buf 0
    glds16(Ab + (long)r0 * lda + c0 * 8, smem + tid * 8);
    glds16(Ab + (long)r0 * lda + c1 * 8, smem + (tid + 256) * 8);
    glds16(Bb + (long)r0 * ldb + c0 * 8, smem + 4096 + tid * 8);
    glds16(Bb + (long)r0 * ldb + c1 * 8, smem + 4096 + (tid + 256) * 8);

    for (int it = 0; it < nIter; ++it) {
        unsigned short* cur = smem + ((it & 1) << 13);
        unsigned short* nxt = smem + (((it + 1) & 1) << 13);
        if (it + 1 < nIter) {
            const int kb = (it + 1) << 5;
            glds16(Ab + (long)r0 * lda + kb + c0 * 8, nxt + tid * 8);
            glds16(Ab + (long)r0 * lda + kb + c1 * 8, nxt + (tid + 256) * 8);
            glds16(Bb + (long)r0 * ldb + kb + c0 * 8, nxt + 4096 + tid * 8);
            glds16(Bb + (long)r0 * ldb + kb + c1 * 8, nxt + 4096 + (tid + 256) * 8);
            SYNC_VM4();   // oldest 4 (cur tile) landed; prefetch still in flight
        } else {
            SYNC_VM0();
        }
        bf16x8 af[4], bfr[4];
#pragma unroll
        for (int mi = 0; mi < 4; mi++)
            af[mi] = *(const bf16x8*)(cur + (q * 128 + wr + mi * 16 + l15) * 8);
#pragma unroll
        for (int ni = 0; ni < 4; ni++)
            bfr[ni] = *(const bf16x8*)(cur + 4096 + (q * 128 + wc + ni * 16 + l15) * 8);
#pragma unroll
        for (int mi = 0; mi < 4; mi++)
#pragma unroll
            for (int ni = 0; ni < 4; ni++)
                acc[mi][ni] = __builtin_amdgcn_mfma_f32_16x16x32_bf16(
                    af[mi], bfr[ni], acc[mi][ni], 0, 0, 0);
        SYNC_LGKM();  // all waves done reading cur -> next iter may overwrite it
    }

    if (EPI == EADJ) __syncthreads();  // all waves done with K-loop LDS before tile reuse

    // Epilogue. C/D layout: col = lane&15, row = (lane>>4)*4 + reg (m89).
    const float* sqb = (EPI == EADJ || EPI == ELAP1 || EPI == ELAP2)
                           ? (sq + (long)bz * NP) : nullptr;
#pragma unroll
    for (int mi = 0; mi < 4; mi++) {
#pragma unroll
        for (int rg = 0; rg < 4; rg++) {
            const int grow = rowBase + wr + mi * 16 + q * 4 + rg;
            float rsumv = 0.f;
            float di = 0.f;
            if (EPI == ELAP1 || EPI == ELAP2) di = sqb[grow];
#pragma unroll
            for (int ni = 0; ni < 4; ni++) {
                const int gcol = colBase + wc + ni * 16 + l15;
                float v = acc[mi][ni][rg];
                long cidx = (long)bz * sC + (long)grow * ldc + gcol;
                if (EPI == EADJ) {
                    float e = __expf(2.f * v - sqb[grow] - sqb[gcol]);
                    unsigned short h = f2b(e);
                    C[cidx] = h;
                    rsumv += e;
                    if (!diag) {
                        const int rl = wr + mi * 16 + q * 4 + rg;  // local row
                        const int cl = wc + ni * 16 + l15;         // local col
                        smem[cl * TPAD + rl] = h;                  // transposed stash
                    }
                } else if (EPI == ELAP1) {
                    // X1 = out - D*(A*(D*out))
                    float o = b2f(aux[(long)bz * sAux + (long)grow * ldaux + gcol]);
                    C[cidx] = f2b(o - di * v);
                } else if (EPI == ELAP2) {
                    // X2 = 2*(X1 - D*(A*(D*X1))) - out
                    long abase = (long)bz * sAux + (long)grow * ldaux + gcol;
                    float o0 = b2f(aux[abase]);          // out  (cat block0)
                    float o1 = b2f(aux[abase + 1024]);   // X1   (cat block1)
                    C[cidx] = f2b(2.f * (o1 - di * v) - o0);
                } else if (EPI == EBRELU) {
                    float bv = (gcol < biasN) ? bias[gcol] : 0.f;
                    float o = v + bv;
                    C[cidx] = f2b(o > 0.f ? o : 0.f);
                } else {  // EACCR: fp32 atomic accumulate (split-K)
                    atomicAdd(&rowsum[(long)grow * ldc + gcol], v);
                }
            }
            if (EPI == EADJ) {
                rsumv += __shfl_xor(rsumv, 1);
                rsumv += __shfl_xor(rsumv, 2);
                rsumv += __shfl_xor(rsumv, 4);
                rsumv += __shfl_xor(rsumv, 8);
                if (l15 == 0) atomicAdd(&rowsum[(long)bz * NP + grow], rsumv);
            }
        }
    }

    if (EPI == EADJ) {
        if (!diag) {
            __syncthreads();
            // Mirror: row cl of the transposed tile -> C[colBase+cl][rowBase..+127],
            // coalesced 128B-per-thread-pair writes; column sums -> rowsum.
            const int cl = tid >> 1, hh = tid & 1;
            const unsigned short* srcp = smem + cl * TPAD + hh * 64;
            unsigned short* dstp = C + (long)bz * sC + (long)(colBase + cl) * ldc
                                 + rowBase + hh * 64;
            float csum = 0.f;
#pragma unroll
            for (int k2 = 0; k2 < 8; k2++) {
                u16x4 v0 = *(const u16x4*)(srcp + k2 * 8);
                u16x4 v1 = *(const u16x4*)(srcp + k2 * 8 + 4);
                u16x8 vv;
                vv[0] = v0[0]; vv[1] = v0[1]; vv[2] = v0[2]; vv[3] = v0[3];
                vv[4] = v1[0]; vv[5] = v1[1]; vv[6] = v1[2]; vv[7] = v1[3];
#pragma unroll
                for (int e2 = 0; e2 < 8; e2++) csum += b2f(vv[e2]);
                *(u16x8*)(dstp + k2 * 8) = vv;
            }
            atomicAdd(&rowsum[(long)bz * NP + colBase + cl], csum);
        }
    }
}

// ---------------------------------------------------------------------------
// Scaled bf16 transpose: dst[c][r] = dv[r] * src[r][c]; grid (cols/64, rows/64, C)
// ---------------------------------------------------------------------------
__global__ __launch_bounds__(256) void k_trs(
    const unsigned short* __restrict__ src, long sS, int ldS,
    const float* __restrict__ dv,
    unsigned short* __restrict__ dst, long sD, int ldD)
{
    __shared__ unsigned short t[64][72];
    const int b = blockIdx.z;
    const int c0 = blockIdx.x * 64, r0 = blockIdx.y * 64;
    const unsigned short* S = src + (long)b * sS;
    const float* dvb = dv + (long)b * NP;
    unsigned short* D = dst + (long)b * sD;
    const int tx = threadIdx.x & 7, ty = threadIdx.x >> 3;
#pragma unroll
    for (int p = 0; p < 2; p++) {
        int r = ty + p * 32;
        float s = dvb[r0 + r];
        u16x8 v = *(const u16x8*)(S + (long)(r0 + r) * ldS + c0 + tx * 8);
#pragma unroll
        for (int k = 0; k < 8; k++) t[tx * 8 + k][r] = f2b(s * b2f(v[k]));
    }
    __syncthreads();
#pragma unroll
    for (int p = 0; p < 2; p++) {
        int r = ty + p * 32;
        u16x8 v;
#pragma unroll
        for (int k = 0; k < 8; k++) v[k] = t[r][tx * 8 + k];
        *(u16x8*)(D + (long)(c0 + r) * ldD + r0 + tx * 8) = v;
    }
}

// fp32 tiled transpose: dst[c*R + r] = src[r*C + c].  grid (ceil(C/32), ceil(R/32)),
// block dim3(32,8).
__global__ void k_trf32(const float* __restrict__ src, int R, int C,
                        float* __restrict__ dst)
{
    __shared__ float t[32][33];
    const int c0 = blockIdx.x * 32, r0 = blockIdx.y * 32;
#pragma unroll
    for (int p = 0; p < 4; p++) {
        int r = r0 + threadIdx.y + p * 8;
        int c = c0 + threadIdx.x;
        t[threadIdx.y + p * 8][threadIdx.x] =
            (r < R && c < C) ? src[(long)r * C + c] : 0.f;
    }
    __syncthreads();
#pragma unroll
    for (int p = 0; p < 4; p++) {
        int c = c0 + threadIdx.y + p * 8;   // dst row
        int r = r0 + threadIdx.x;           // dst col
        if (c < C && r < R) dst[(long)c * R + r] = t[threadIdx.x][threadIdx.y + p * 8];
    }
}

// ---------------------------------------------------------------------------
// Permuted+transposed weight fill: dst[o][s*FP+f] = W[(f*KK+s)*1000+o], 0-pad.
// grid (16, dstld/64), 256 thr.
// ---------------------------------------------------------------------------
__global__ __launch_bounds__(256) void k_wperm(
    const float* __restrict__ W, unsigned short* __restrict__ dst, int KK, int dstld)
{
    __shared__ float tile[64][65];
    const int o0 = blockIdx.x * 64;
    const int kk0 = blockIdx.y * 64;
    const int s = kk0 >> 10;
    const int fbase = kk0 & 1023;
    const int ci = threadIdx.x & 63;
    const int ri = threadIdx.x >> 6;
#pragma unroll 4
    for (int p = 0; p < 16; p++) {
        int fi = fbase + ri + p * 4;
        int oi = o0 + ci;
        float v = 0.f;
        if (fi < 1000 && oi < 1000) v = W[((long)fi * KK + s) * 1000 + oi];
        tile[ri + p * 4][ci] = v;
    }
    __syncthreads();
#pragma unroll 4
    for (int p = 0; p < 16; p++) {
        int orow = ri + p * 4;
        dst[(long)(o0 + orow) * dstld + kk0 + ci] = f2b(tile[ci][orow]);
    }
}

// zero-init of accumulators + catr pad rows + vr/accR (for atomics).
__global__ void k_zinit(float* __restrict__ rs2, float* __restrict__ g,
                        float* __restrict__ racc, unsigned short* __restrict__ catrpad,
                        float* __restrict__ dv1, float* __restrict__ xacc1,
                        float* __restrict__ xacc2, float* __restrict__ yacc1,
                        float* __restrict__ yacc2, float* __restrict__ l2acc,
                        float* __restrict__ vr, float* __restrict__ sqc,
                        float* __restrict__ accR)
{
    long i = (long)blockIdx.x * 256 + threadIdx.x;
    if (i < (long)BB * NP) { rs2[i] = 0.f; dv1[i] = 0.f; sqc[i] = 0.f; }
    if (i < (long)BB * FP) g[i] = 0.f;
    if (i < 64) racc[i] = 0.f;
    if (i < (long)(MRp - 320) * RK) catrpad[i] = 0;
    if (i < (long)BB * 6 * NP) { xacc1[i] = 0.f; xacc2[i] = 0.f; l2acc[i] = 0.f; }
    if (i < (long)BB * 6 * FP) { yacc1[i] = 0.f; yacc2[i] = 0.f; }
    if (i < (long)BB * RR * FP) vr[i] = 0.f;
    if (i < (long)MRp * FP) accR[i] = 0.f;
}

// x (B,N,6) -> x6t (B,6,N) + sqx (B,N).  grid (8, BB)
__global__ void k_xprep(const float* __restrict__ x, float* __restrict__ x6t,
                        float* __restrict__ sqx)
{
    const int b = blockIdx.y;
    const int j = blockIdx.x * 256 + threadIdx.x;
    float s = 0.f;
#pragma unroll
    for (int c = 0; c < 6; c++) {
        float v = x[((long)b * NP + j) * 6 + c];
        x6t[(long)b * 6 * NP + c * NP + j] = v;
        s += v * v;
    }
    sqx[(long)b * NP + j] = s;
}

// x-graph laplacian passes, j-split across NJ chunks with atomic reduction.
// grid (8, NJ, BB), block 256.
template <int MODE>
__global__ __launch_bounds__(256) void k_lapj(
    const float* __restrict__ x6t, const float* __restrict__ sqx,
    const float* __restrict__ dv1, const float* __restrict__ srct,
    float* __restrict__ acc)
{
    const int b = blockIdx.z;
    const int row = blockIdx.x * 256 + threadIdx.x;
    const int j0 = blockIdx.y * (NP / NJ);
    const float* xt = x6t + (long)b * 6 * NP;
    const float* sq = sqx + (long)b * NP;
    float xi[6];
#pragma unroll
    for (int c = 0; c < 6; c++) xi[c] = xt[c * NP + row];
    const float sqi = sq[row];
    const float* dv = (MODE >= 1) ? (dv1 + (long)b * NP) : nullptr;
    const float* st = (MODE >= 1) ? (srct + (long)b * 6 * NP) : nullptr;
    float s0 = 0.f;
    float sc[6] = {0, 0, 0, 0, 0, 0};
    for (int j = j0; j < j0 + NP / NJ; j++) {
        float dot = 0.f;
#pragma unroll
        for (int c = 0; c < 6; c++) dot += xi[c] * xt[c * NP + j];
        float e = __expf(2.f * dot - sqi - sq[j]);
        if (MODE == 0) {
            s0 += e;
        } else {
            float wgt = e * dv[j];
#pragma unroll
            for (int c = 0; c < 6; c++) sc[c] += wgt * st[c * NP + j];
        }
    }
    if (MODE == 0) {
        atomicAdd(&acc[(long)b * NP + row], s0);
    } else {
#pragma unroll
        for (int c = 0; c < 6; c++)
            atomicAdd(&acc[(long)b * 6 * NP + c * NP + row], sc[c]);
    }
}

// finalize lap pass: MODE 1: out = xi - di*sc ; MODE 2: out = 2*(x1-di*sc)-xi
// grid (8, B') block 256
template <int MODE>
__global__ void k_lfin(const float* __restrict__ x6t, const float* __restrict__ dv1,
                       const float* __restrict__ xacc, const float* __restrict__ x1t6,
                       float* __restrict__ outv)
{
    const int b = blockIdx.y;
    const int row = blockIdx.x * 256 + threadIdx.x;
    const float di = dv1[(long)b * NP + row];
#pragma unroll
    for (int c = 0; c < 6; c++) {
        long idx = (long)b * 6 * NP + c * NP + row;
        float xi = x6t[idx];
        float sc = xacc[idx];
        if (MODE == 1) outv[idx] = xi - di * sc;
        else           outv[idx] = 2.f * (x1t6[idx] - di * sc) - xi;
    }
}

// adjx: l2acc[b,c,row] += sum_{j in chunk} adj[row][j] * dv[j] * x6t[c][j]
// grid (NP/64, NJ2, C), block 256 (64 rows x 4 lanes).
__global__ __launch_bounds__(256) void k_adjx(
    const unsigned short* __restrict__ adj, const float* __restrict__ dv,
    const float* __restrict__ x6t, float* __restrict__ l2acc)
{
    __shared__ float xs[6][256];
    __shared__ float dvs[256];
    __shared__ float lsum[64][4][6];
    const int b = blockIdx.z;
    const int j0 = blockIdx.y * (NP / NJ2);   // 256-col chunk
    if (threadIdx.x < 256) dvs[threadIdx.x] = dv[(long)b * NP + j0 + threadIdx.x];
    for (int e = threadIdx.x; e < 6 * 256; e += 256) {
        int c = e >> 8, j = e & 255;
        xs[c][j] = x6t[(long)b * 6 * NP + c * NP + j0 + j];
    }
    __syncthreads();
    const int ty = threadIdx.x >> 2;
    const int tx = threadIdx.x & 3;
    const int grow = blockIdx.x * 64 + ty;
    const unsigned short* rowp = adj + (long)b * NP * NP + (long)grow * NP + j0;
    float sc[6] = {0, 0, 0, 0, 0, 0};
    for (int it = 0; it < 8; it++) {
        int col = it * 32 + tx * 8;
        u16x8 a8 = *(const u16x8*)(rowp + col);
#pragma unroll
        for (int k = 0; k < 8; k++) {
            float w = b2f(a8[k]) * dvs[col + k];
#pragma unroll
            for (int c = 0; c < 6; c++) sc[c] += w * xs[c][col + k];
        }
    }
#pragma unroll
    for (int c = 0; c < 6; c++) lsum[ty][tx][c] = sc[c];
    __syncthreads();
    for (int e = threadIdx.x; e < 64 * 6; e += 256) {
        int row = e / 6, c = e % 6;
        float t = lsum[row][0][c] + lsum[row][1][c] + lsum[row][2][c] + lsum[row][3][c];
        atomicAdd(&l2acc[(long)b * 6 * NP + (long)c * NP + blockIdx.x * 64 + row], t);
    }
}

// cheb1: out = relu([x|x1|x2] @ W1 + b1) -> cat block0 (bf16, pad 0) + fused
// sqc accumulation (squares of the bf16-ROUNDED values -> adj diagonal exact).
// grid (16 ntile, 4 ftile, C)
__global__ __launch_bounds__(256) void k_cheb1(
    const float* __restrict__ x, const float* __restrict__ x1t6,
    const float* __restrict__ x2t6, const float* __restrict__ W1,
    const float* __restrict__ b1, unsigned short* __restrict__ cat,
    float* __restrict__ sqc)
{
    __shared__ float xk[128 * 18];
    __shared__ float rs[128];
    const int b = blockIdx.z;
    const int n0 = blockIdx.x * 128;
    const int f0 = blockIdx.y * 256;
    for (int e = threadIdx.x; e < 128 * 18; e += 256) {
        int rown = e / 18, c18 = e % 18;
        int cc = c18 / 3, kk = c18 % 3;
        int n = n0 + rown;
        float v;
        if (kk == 0) v = x[((long)b * NP + n) * 6 + cc];
        else if (kk == 1) v = x1t6[(long)b * 6 * NP + cc * NP + n];
        else v = x2t6[(long)b * 6 * NP + cc * NP + n];
        xk[e] = v;
    }
    if (threadIdx.x < 128) rs[threadIdx.x] = 0.f;
    __syncthreads();
    const int lane = threadIdx.x & 63;
    for (int gi = threadIdx.x; gi < 128 * 64; gi += 256) {
        int rown = gi >> 6;   // uniform across each wave for a given iteration
        int f4 = f0 + (gi & 63) * 4;
        float a0 = 0, a1 = 0, a2 = 0, a3 = 0;
        if (f4 < 1000) {
            a0 = b1[f4]; a1 = b1[f4 + 1]; a2 = b1[f4 + 2]; a3 = b1[f4 + 3];
#pragma unroll
            for (int cI = 0; cI < 18; cI++) {
                float xv = xk[rown * 18 + cI];
                f32x4 w = *(const f32x4*)(W1 + cI * 1000 + f4);
                a0 += xv * w[0]; a1 += xv * w[1]; a2 += xv * w[2]; a3 += xv * w[3];
            }
            a0 = a0 > 0 ? a0 : 0; a1 = a1 > 0 ? a1 : 0;
            a2 = a2 > 0 ? a2 : 0; a3 = a3 > 0 ? a3 : 0;
        }
        u16x4 o;
        o[0] = f2b(a0); o[1] = f2b(a1); o[2] = f2b(a2); o[3] = f2b(a3);
        *(u16x4*)(cat + (long)b * NP * K3 + (long)(n0 + rown) * K3 + f4) = o;
        float r0 = b2f(o[0]), r1 = b2f(o[1]), r2 = b2f(o[2]), r3 = b2f(o[3]);
        float s2 = r0 * r0 + r1 * r1 + r2 * r2 + r3 * r3;
        // rown is wave-uniform: wave-reduce then one LDS atomic
#pragma unroll
        for (int d = 1; d < 64; d <<= 1) s2 += __shfl_xor(s2, d);
        if (lane == 0) atomicAdd(&rs[rown], s2);
    }
    __syncthreads();
    if (threadIdx.x < 128)
        atomicAdd(&sqc[(long)b * NP + n0 + threadIdx.x], rs[threadIdx.x]);
}

__global__ void k_rsqrt(float* __restrict__ p) {
    int i = blockIdx.x * 256 + threadIdx.x;
    p[i] = rsqrtf(p[i]);
}

// vertices_Reeb: vr[b,r,f] = max_g out[b,sccs[b,r,g],f].  grid (RR, C, 4 gchunk).
// fp32-as-int atomicMax valid: relu outputs >= 0; vr zero-init.
__global__ void k_vr(const unsigned short* __restrict__ cat,
                     const int* __restrict__ sccs, float* __restrict__ vr)
{
    const int b = blockIdx.y, r = blockIdx.x;
    const int g0 = blockIdx.z * (GG / 4);
    const int f4 = threadIdx.x * 4;
    const int* sp = sccs + ((long)b * RR + r) * GG;
    float m0 = 0.f, m1 = 0.f, m2 = 0.f, m3 = 0.f;
    for (int g = g0; g < g0 + GG / 4; g++) {
        int idx = sp[g];
        u16x4 v = *(const u16x4*)(cat + ((long)b * NP + idx) * K3 + f4);
        m0 = fmaxf(m0, b2f(v[0])); m1 = fmaxf(m1, b2f(v[1]));
        m2 = fmaxf(m2, b2f(v[2])); m3 = fmaxf(m3, b2f(v[3]));
    }
    float* op = vr + ((long)b * RR + r) * FP + f4;
    atomicMax((int*)&op[0], __float_as_int(m0));
    atomicMax((int*)&op[1], __float_as_int(m1));
    atomicMax((int*)&op[2], __float_as_int(m2));
    atomicMax((int*)&op[3], __float_as_int(m3));
}

// Reeb Chebyshev recursion (fp32), f-parallel. grid (4, BB), one f per thread.
__global__ __launch_bounds__(256) void k_reeb(
    const float* __restrict__ vr, const float* __restrict__ lapR,
    unsigned short* __restrict__ catr)
{
    __shared__ float Lr[RR * RR];
    const int b = blockIdx.y;
    for (int e = threadIdx.x; e < RR * RR; e += 256) Lr[e] = lapR[(long)b * RR * RR + e];
    __syncthreads();
    const int f = blockIdx.x * 256 + threadIdx.x;
    float xa[RR], xb[RR], xc[RR];
#pragma unroll
    for (int r = 0; r < RR; r++) xa[r] = vr[((long)b * RR + r) * FP + f];
#pragma unroll
    for (int r = 0; r < RR; r++) catr[((long)b * RR + r) * RK + f] = f2b(xa[r]);
#pragma unroll
    for (int r = 0; r < RR; r++) {
        float s = 0.f;
#pragma unroll
        for (int qq = 0; qq < RR; qq++) s += Lr[r * RR + qq] * xa[qq];
        xb[r] = s;
    }
#pragma unroll
    for (int r = 0; r < RR; r++) catr[((long)b * RR + r) * RK + FP + f] = f2b(xb[r]);
    for (int st = 2; st < 6; st++) {
#pragma unroll
        for (int r = 0; r < RR; r++) {
            float s = 0.f;
#pragma unroll
            for (int qq = 0; qq < RR; qq++) s += Lr[r * RR + qq] * xb[qq];
            xc[r] = 2.f * s - xa[r];
        }
#pragma unroll
        for (int r = 0; r < RR; r++)
            catr[((long)b * RR + r) * RK + st * FP + f] = f2b(xc[r]);
#pragma unroll
        for (int r = 0; r < RR; r++) { xa[r] = xb[r]; xb[r] = xc[r]; }
    }
}

// Reeb split-K finalize: outr = bf16(relu(accR + br)).  grid (4, 320)
__global__ void k_rfin(const float* __restrict__ accR, const float* __restrict__ br,
                       unsigned short* __restrict__ outr)
{
    const int f = blockIdx.x * 256 + threadIdx.x;
    const int m = blockIdx.y;
    float bv = (f < 1000) ? br[f] : 0.f;
    float v = accR[(long)m * FP + f] + bv;
    outr[(long)m * FP + f] = f2b(v > 0.f ? v : 0.f);
}

__global__ void k_grmax(const unsigned short* __restrict__ outr, float* __restrict__ gr)
{  // grid (4, BB)
    const int b = blockIdx.y;
    const int f = blockIdx.x * 256 + threadIdx.x;
    float m = -1e30f;
    for (int r = 0; r < RR; r++)
        m = fmaxf(m, b2f(outr[((long)b * RR + r) * FP + f]));
    gr[(long)b * FP + f] = (f < 1000) ? m : 0.f;
}

// rnorm stage 1: yacc[b,c,f] += sum_{i in chunk} mat[b,i,f] * v6[b,c,i]
// optional fused column-max (gm != nullptr, values >= 0, gm zero-init).
// grid (4 fblk, NI, C) block 256
__global__ __launch_bounds__(256) void k_rnacc(
    const unsigned short* __restrict__ mat, long sM, int ldm,
    const float* __restrict__ vt6, float* __restrict__ yacc,
    float* __restrict__ gm)
{
    const int b = blockIdx.z;
    const int f = blockIdx.x * 256 + threadIdx.x;
    const int i0 = blockIdx.y * (NP / NI);
    const unsigned short* mp = mat + (long)b * sM + f;
    const float* vp = vt6 + (long)b * 6 * NP;
    float a[6] = {0, 0, 0, 0, 0, 0};
    float mx = 0.f;
    for (int i = i0; i < i0 + NP / NI; i++) {
        float o = b2f(mp[(long)i * ldm]);
        if (gm) mx = fmaxf(mx, o);
#pragma unroll
        for (int c = 0; c < 6; c++) a[c] += o * vp[c * NP + i];
    }
#pragma unroll
    for (int c = 0; c < 6; c++)
        atomicAdd(&yacc[((long)b * 6 + c) * FP + f], a[c]);
    if (gm) atomicMax((int*)&gm[(long)b * FP + f], __float_as_int(mx));
}

// rnorm stage 2: racc[bi] += partial sum of yacc^2.  grid (2, 16) block 256
__global__ void k_rnred(const float* __restrict__ yacc1,
                        const float* __restrict__ yacc2, float* __restrict__ racc)
{
    __shared__ float red[256];
    const float* y = (blockIdx.x == 0) ? yacc1 : yacc2;
    const long tot = (long)BB * 6 * FP;
    const long per = tot / 16;
    const long e0 = blockIdx.y * per;
    float s = 0.f;
    for (long e = e0 + threadIdx.x; e < e0 + per; e += 256) {
        float v = y[e];
        s += v * v;
    }
    red[threadIdx.x] = s;
    __syncthreads();
    for (int st = 128; st > 0; st >>= 1) {
        if (threadIdx.x < st) red[threadIdx.x] += red[threadIdx.x + st];
        __syncthreads();
    }
    if (threadIdx.x == 0) atomicAdd(&racc[blockIdx.x], red[0]);
}

// h1 = relu([gR|g] @ Wfc1 + bfc1), wave-per-output with WT1 (512 x 2000).
// grid (128, BB) block 256 (4 waves)
__global__ __launch_bounds__(256) void k_fc1w(
    const float* __restrict__ gr, const float* __restrict__ g,
    const float* __restrict__ WT1, const float* __restrict__ bias,
    float* __restrict__ h1)
{
    const int b = blockIdx.y;
    const int lane = threadIdx.x & 63;
    const int o = blockIdx.x * 4 + (threadIdx.x >> 6);
    const float* wt = WT1 + (long)o * 2000;
    const float* grp = gr + (long)b * FP;
    const float* gp = g + (long)b * FP;
    float s = 0.f;
    for (int j0 = 0; j0 < 2000; j0 += 64) {
        int j = j0 + lane;
        if (j < 2000) {
            float fv = (j < 1000) ? grp[j] : gp[j - 1000];
            s += fv * wt[j];
        }
    }
#pragma unroll
    for (int d = 1; d < 64; d <<= 1) s += __shfl_xor(s, d);
    if (lane == 0) {
        float v = s + bias[o];
        h1[(long)b * 512 + o] = v > 0.f ? v : 0.f;
    }
}

// h2 = relu(h1 @ Wfc2 + bfc2), wave-per-output with WT2 (128 x 512).
// grid (32, BB) block 256
__global__ __launch_bounds__(256) void k_fc2w(
    const float* __restrict__ h1, const float* __restrict__ WT2,
    const float* __restrict__ bias, float* __restrict__ h2)
{
    const int b = blockIdx.y;
    const int lane = threadIdx.x & 63;
    const int o = blockIdx.x * 4 + (threadIdx.x >> 6);
    const float* wt = WT2 + (long)o * 512;
    const float* hp = h1 + (long)b * 512;
    float s = 0.f;
#pragma unroll
    for (int j0 = 0; j0 < 512; j0 += 64) s += hp[j0 + lane] * wt[j0 + lane];
#pragma unroll
    for (int d = 1; d < 64; d <<= 1) s += __shfl_xor(s, d);
    if (lane == 0) {
        float v = s + bias[o];
        h2[(long)b * 128 + o] = v > 0.f ? v : 0.f;
    }
}

// final FC + regs.  grid(4) block 256: blk0=FC3, blk1/2/3 = weight-norm sums.
__global__ void k_tail(const float* __restrict__ h2, const float* __restrict__ Wfc3,
                       const float* __restrict__ bfc3, const float* __restrict__ Wfc1,
                       const float* __restrict__ bfc1, const float* __restrict__ Wfc2,
                       const float* __restrict__ bfc2, const float* __restrict__ racc,
                       float* __restrict__ out)
{
    if (blockIdx.x == 0) {
        for (int e = threadIdx.x; e < 640; e += 256) {
            int row = e / 40, o = e % 40;
            float s = bfc3[o];
            for (int j = 0; j < 128; j++) s += h2[row * 128 + j] * Wfc3[j * 40 + o];
            out[e] = s;
        }
        return;
    }
    __shared__ float red[256];
    float s = 0.f;
    if (blockIdx.x == 1) {
        for (int j = threadIdx.x; j < 2000; j += 256) { float w = Wfc1[j * 512]; s += w * w; }
    } else if (blockIdx.x == 2) {
        for (int j = threadIdx.x; j < 512; j += 256) { float w = Wfc2[j * 128]; s += w * w; }
    } else {
        for (int j = threadIdx.x; j < 128; j += 256) { float w = Wfc3[j * 40]; s += w * w; }
    }
    red[threadIdx.x] = s;
    __syncthreads();
    for (int st = 128; st > 0; st >>= 1) {
        if (threadIdx.x < st) red[threadIdx.x] += red[threadIdx.x + st];
        __syncthreads();
    }
    if (threadIdx.x == 0) {
        if (blockIdx.x == 1) out[642] = red[0];
        else if (blockIdx.x == 2) out[644] = red[0];
        else {
            out[646] = red[0];
            out[640] = sqrtf(racc[0]);
            out[641] = sqrtf(racc[1]);
            out[643] = bfc1[0] * bfc1[0];
            out[645] = bfc2[0] * bfc2[0];
            out[647] = bfc3[0] * bfc3[0];
        }
    }
}

// ---------------------------------------------------------------------------
extern "C" void kernel_launch(void* const* d_in, const int* in_sizes, int n_in,
                              void* d_out, int out_size, void* d_ws, size_t ws_size,
                              hipStream_t stream)
{
    (void)in_sizes; (void)n_in; (void)out_size;
    const float* x    = (const float*)d_in[0];
    const float* lapR = (const float*)d_in[1];
    const int*   sccs = (const int*)d_in[2];
    const float* W1   = (const float*)d_in[3];
    const float* b1   = (const float*)d_in[4];
    const float* W2   = (const float*)d_in[5];
    const float* b2   = (const float*)d_in[6];
    const float* Wr   = (const float*)d_in[7];
    const float* br   = (const float*)d_in[8];
    const float* Wfc1 = (const float*)d_in[9];
    const float* bfc1 = (const float*)d_in[10];
    const float* Wfc2 = (const float*)d_in[11];
    const float* bfc2 = (const float*)d_in[12];
    const float* Wfc3 = (const float*)d_in[13];
    const float* bfc3 = (const float*)d_in[14];
    float* out = (float*)d_out;

    char* w = (char*)d_ws;
    size_t used = 0;
    auto alloc = [&](size_t bytes) {
        char* p = w + used;
        used += (bytes + 255) & ~(size_t)255;
        return p;
    };
    // ---- persistent buffers (~39 MB) ----
    unsigned short* w2pt = (unsigned short*)alloc((size_t)FP * K3 * 2);
    unsigned short* wrpt = (unsigned short*)alloc((size_t)FP * RK * 2);
    unsigned short* catr = (unsigned short*)alloc((size_t)MRp * RK * 2);
    unsigned short* outr = (unsigned short*)alloc((size_t)MRp * FP * 2);
    float* accR = (float*)alloc((size_t)MRp * FP * 4);
    float* vr   = (float*)alloc((size_t)BB * RR * FP * 4);
    float* x6t  = (float*)alloc((size_t)BB * 6 * NP * 4);
    float* sqx  = (float*)alloc((size_t)BB * NP * 4);
    float* dv1  = (float*)alloc((size_t)BB * NP * 4);
    float* x1t6 = (float*)alloc((size_t)BB * 6 * NP * 4);
    float* x2t6 = (float*)alloc((size_t)BB * 6 * NP * 4);
    float* xacc1= (float*)alloc((size_t)BB * 6 * NP * 4);
    float* xacc2= (float*)alloc((size_t)BB * 6 * NP * 4);
    float* l2acc= (float*)alloc((size_t)BB * 6 * NP * 4);
    float* sqc  = (float*)alloc((size_t)BB * NP * 4);
    float* rs2  = (float*)alloc((size_t)BB * NP * 4);
    float* l2xt6= (float*)alloc((size_t)BB * 6 * NP * 4);
    float* g    = (float*)alloc((size_t)BB * FP * 4);
    float* gr   = (float*)alloc((size_t)BB * FP * 4);
    float* h1   = (float*)alloc((size_t)BB * 512 * 4);
    float* h2   = (float*)alloc((size_t)BB * 128 * 4);
    float* racc = (float*)alloc(256);
    float* WT1  = (float*)alloc((size_t)512 * 2000 * 4);
    float* WT2  = (float*)alloc((size_t)128 * 512 * 4);
    float* yacc1= (float*)alloc((size_t)BB * 6 * FP * 4);
    float* yacc2= (float*)alloc((size_t)BB * 6 * FP * 4);

    // ---- choose batch chunk size C so chunk buffers fit ws ----
    const size_t PCAT = (size_t)NP * K3 * 2;   // 12.58 MB / batch
    const size_t PA   = (size_t)NP * NP * 2;   //  8.39 MB / batch (adj; out2 aliases)
    const size_t PTT  = (size_t)FP * NP * 2;   //  4.19 MB / batch
    int C = 16;
    while (C > 1 && used + (size_t)C * (PCAT + PA + PTT) + 4096 > ws_size) C >>= 1;
    if (used + (size_t)C * (PCAT + PA + PTT) + 4096 > ws_size) return;  // ws too small

    unsigned short* cat_c = (unsigned short*)alloc((size_t)C * PCAT);
    unsigned short* a_c   = (unsigned short*)alloc((size_t)C * PA);
    unsigned short* tt_c  = (unsigned short*)alloc((size_t)C * PTT);
    unsigned short* out2_c = a_c;  // alias: adj dead once G4 runs

    const long sCat = (long)NP * K3;
    const long sL2  = (long)NP * NP;
    const long sTT  = (long)FP * NP;
    const long sO2  = (long)NP * FP;

    // zero inits (ws is re-poisoned to 0xAA before every timed call)
    k_zinit<<<dim3(1536), 256, 0, stream>>>(rs2, g, racc, catr + (size_t)320 * RK,
                                            dv1, xacc1, xacc2, yacc1, yacc2, l2acc,
                                            vr, sqc, accR);

    // weight prep
    k_wperm<<<dim3(16, K3 / 64), 256, 0, stream>>>(W2, w2pt, 3, K3);
    k_wperm<<<dim3(16, RK / 64), 256, 0, stream>>>(Wr, wrpt, 6, RK);
    k_trf32<<<dim3(16, 63), dim3(32, 8), 0, stream>>>(Wfc1, 2000, 512, WT1);
    k_trf32<<<dim3(4, 16), dim3(32, 8), 0, stream>>>(Wfc2, 512, 128, WT2);

    // x-graph laplacian path (fp32, full batch, j-split + atomic reduce)
    k_xprep<<<dim3(8, BB), 256, 0, stream>>>(x, x6t, sqx);
    k_lapj<0><<<dim3(8, NJ, BB), 256, 0, stream>>>(x6t, sqx, nullptr, nullptr, dv1);
    k_rsqrt<<<dim3(BB * NP / 256), 256, 0, stream>>>(dv1);
    k_lapj<1><<<dim3(8, NJ, BB), 256, 0, stream>>>(x6t, sqx, dv1, x6t, xacc1);
    k_lfin<1><<<dim3(8, BB), 256, 0, stream>>>(x6t, dv1, xacc1, nullptr, x1t6);
    k_lapj<2><<<dim3(8, NJ, BB), 256, 0, stream>>>(x6t, sqx, dv1, x1t6, xacc2);
    k_lfin<2><<<dim3(8, BB), 256, 0, stream>>>(x6t, dv1, xacc2, x1t6, x2t6);

    for (int c0 = 0; c0 < BB; c0 += C) {
        const float* xc  = x     + (long)c0 * NP * 6;
        const float* x6c = x6t   + (long)c0 * 6 * NP;
        const float* x1c = x1t6  + (long)c0 * 6 * NP;
        const float* x2c = x2t6  + (long)c0 * 6 * NP;
        float*       sqcc= sqc   + (long)c0 * NP;
        float*       rsc = rs2   + (long)c0 * NP;
        float*       l2ac= l2acc + (long)c0 * 6 * NP;
        float*       l2xc= l2xt6 + (long)c0 * 6 * NP;

        // cheb1 -> cat block0 (out, bf16) + fused sqc
        k_cheb1<<<dim3(16, 4, C), 256, 0, stream>>>(xc, x1c, x2c, W1, b1, cat_c, sqcc);

        // G1 (symmetric): triangle tiles only + mirror write; rowsums -> rsc
        gemm_bt<EADJ><<<dim3(136, 1, C), 256, 0, stream>>>(
            cat_c, sCat, K3, cat_c, sCat, K3, a_c, sL2, NP, FP,
            sqcc, rsc, nullptr, 0, 0, nullptr, 0);
        k_rsqrt<<<dim3(C * NP / 256), 256, 0, stream>>>(rsc);

        // L2@x for reg-norm: l2x = x - D*(A*(D*x))   (reads adj once, no write-back)
        k_adjx<<<dim3(NP / 64, NJ2, C), 256, 0, stream>>>(a_c, rsc, x6c, l2ac);
        k_lfin<1><<<dim3(8, C), 256, 0, stream>>>(x6c, rsc, l2ac, nullptr, l2xc);

        // G2: X1 = out - D*(A*(D*out))  (B = (D*out)^T via scaled transpose)
        k_trs<<<dim3(16, 32, C), 256, 0, stream>>>(cat_c, sCat, K3, rsc, tt_c, sTT, NP);
        gemm_bt<ELAP1><<<dim3(8, 16, C), 256, 0, stream>>>(
            a_c, sL2, NP, tt_c, sTT, NP, cat_c + 1024, sCat, K3, NP,
            rsc, nullptr, cat_c, sCat, K3, nullptr, 0);

        // G3: X2 = 2*(X1 - D*(A*(D*X1))) - out
        k_trs<<<dim3(16, 32, C), 256, 0, stream>>>(cat_c + 1024, sCat, K3, rsc, tt_c, sTT, NP);
        gemm_bt<ELAP2><<<dim3(8, 16, C), 256, 0, stream>>>(
            a_c, sL2, NP, tt_c, sTT, NP, cat_c + 2048, sCat, K3, NP,
            rsc, nullptr, cat_c, sCat, K3, nullptr, 0);

        // G4: out2 = relu(cat @ W2perm^T + b2)   (out2 overwrites adj region)
        gemm_bt<EBRELU><<<dim3(8, 16, C), 256, 0, stream>>>(
            cat_c, sCat, K3, w2pt, 0, K3, out2_c, sO2, FP, K3,
            nullptr, nullptr, nullptr, 0, 0, b2, 1000);

        // pools + regs for this chunk (gmax fused into out2 rnacc pass)
        k_vr<<<dim3(RR, C, 4), 256, 0, stream>>>(
            cat_c, sccs + (long)c0 * RR * GG, vr + (long)c0 * RR * FP);
        k_rnacc<<<dim3(4, NI, C), 256, 0, stream>>>(
            cat_c, sCat, K3, x1c, yacc1 + (long)c0 * 6 * FP, nullptr);
        k_rnacc<<<dim3(4, NI, C), 256, 0, stream>>>(
            out2_c, sO2, FP, l2xc, yacc2 + (long)c0 * 6 * FP, g + (long)c0 * FP);
    }

    // Reeb branch (full batch, f-parallel; gemm split-K over 4 chunks)
    k_reeb<<<dim3(4, BB), 256, 0, stream>>>(vr, lapR, catr);
    gemm_bt<EACCR><<<dim3(8, 3, 4), 256, 0, stream>>>(
        catr, 0, RK, wrpt, 0, RK, outr, 0, FP, RK / 4,
        nullptr, accR, nullptr, 0, 0, nullptr, 0);
    k_rfin<<<dim3(4, 320), 256, 0, stream>>>(accR, br, outr);
    k_grmax<<<dim3(4, BB), 256, 0, stream>>>(outr, gr);

    // regs stage 2 + FC head
    k_rnred<<<dim3(2, 16), 256, 0, stream>>>(yacc1, yacc2, racc);
    k_fc1w<<<dim3(128, BB), 256, 0, stream>>>(gr, g, WT1, bfc1, h1);
    k_fc2w<<<dim3(32, BB), 256, 0, stream>>>(h1, WT2, bfc2, h2);
    k_tail<<<dim3(4), 256, 0, stream>>>(h2, Wfc3, bfc3, Wfc1, bfc1, Wfc2, bfc2, racc, out);
}